// Round 4
// baseline (800.638 us; speedup 1.0000x reference)
//
#include <hip/hip_runtime.h>
#include <math.h>

#define IN_DIM 256
#define FDIM 256      // HEADS*HID == OUT == 256
#define HEADS 4
#define NEG 0.2f

typedef __attribute__((ext_vector_type(8))) short bf16x8;
typedef __attribute__((ext_vector_type(8))) unsigned short u16x8;
typedef __attribute__((ext_vector_type(4))) float f32x4;

__device__ __forceinline__ float leaky(float x){ return x > 0.f ? x : NEG * x; }

__device__ __forceinline__ unsigned short f2bf(float f){
  unsigned int u = __float_as_uint(f);
  unsigned int r = u + 0x7fffu + ((u >> 16) & 1u);   // round-to-nearest-even
  return (unsigned short)(r >> 16);
}
__device__ __forceinline__ float bf2f(unsigned short s){
  return __uint_as_float(((unsigned int)s) << 16);
}

__device__ __forceinline__ float4 bcast4(float4 v){
  return make_float4(__shfl(v.x,0,64), __shfl(v.y,0,64), __shfl(v.z,0,64), __shfl(v.w,0,64));
}

__device__ __forceinline__ void gld_lds16(const void* g, void* l){
  __builtin_amdgcn_global_load_lds((const __attribute__((address_space(1))) unsigned int*)g,
                                   (__attribute__((address_space(3))) unsigned int*)l, 16, 0, 0);
}

// ------------------------- CSR build -------------------------
__global__ void k_hist(const int* __restrict__ dst, int* deg, int E){
  int e = blockIdx.x * blockDim.x + threadIdx.x;
  if (e < E) atomicAdd(&deg[dst[e]], 1);
}

__global__ void k_scanA(const int* __restrict__ deg, int* tmp, int* partials, int n){
  __shared__ int sm[256];
  int i = blockIdx.x * 256 + threadIdx.x;
  int v = (i < n) ? deg[i] + 1 : 0;     // +1: self loop
  sm[threadIdx.x] = v; __syncthreads();
  for (int off = 1; off < 256; off <<= 1){
    int x = (threadIdx.x >= off) ? sm[threadIdx.x - off] : 0;
    __syncthreads();
    sm[threadIdx.x] += x;
    __syncthreads();
  }
  if (i < n) tmp[i] = sm[threadIdx.x];            // inclusive within block
  if (threadIdx.x == 255) partials[blockIdx.x] = sm[255];
}

__global__ void k_scanB(int* partials, int nb){   // single block of 1024
  __shared__ int sm[1024];
  int t = threadIdx.x;
  int v = (t < nb) ? partials[t] : 0;
  sm[t] = v; __syncthreads();
  for (int off = 1; off < 1024; off <<= 1){
    int x = (t >= off) ? sm[t - off] : 0;
    __syncthreads();
    sm[t] += x;
    __syncthreads();
  }
  if (t < nb) partials[t] = sm[t] - v;            // exclusive
}

__global__ void k_scanC(const int* __restrict__ tmp, const int* __restrict__ deg,
                        const int* __restrict__ partials, int* rowptr, int n){
  int i = blockIdx.x * blockDim.x + threadIdx.x;
  if (i < n){
    int incl = tmp[i] + partials[i >> 8];
    rowptr[i] = incl - (deg[i] + 1);
    if (i == n - 1) rowptr[n] = incl;             // total = E + n
  }
}

__global__ void k_fill(const int* __restrict__ src, const int* __restrict__ dst,
                       const int* __restrict__ rowptr, int* fill, int* col, int E, int n){
  int e = blockIdx.x * blockDim.x + threadIdx.x;
  if (e < E + n){
    int s, d;
    if (e < E){ s = src[e]; d = dst[e]; } else { s = d = e - E; }
    int pos = atomicAdd(&fill[d], 1);
    col[rowptr[d] + pos] = s;
  }
}

// ------------------------- fused: x fp32->bf16 cast (padded) + W1/W2 transpose-cast -------------------------
__global__ void k_castwt(const float* __restrict__ x, unsigned short* __restrict__ xb, int M, int castBlocks,
                         const float* __restrict__ W1, unsigned short* __restrict__ W1t,
                         const float* __restrict__ W2, unsigned short* __restrict__ W2t){
  int b = blockIdx.x;
  if (b < castBlocks){
    int idx = b * 256 + threadIdx.x;   // one ushort4 group per thread
    int row = idx >> 6;
    float4 v = make_float4(0.f, 0.f, 0.f, 0.f);
    if (row < M) v = *(const float4*)(x + (size_t)idx * 4);
    ushort4 o;
    o.x = f2bf(v.x); o.y = f2bf(v.y); o.z = f2bf(v.z); o.w = f2bf(v.w);
    *(ushort4*)(xb + (size_t)idx * 4) = o;
  } else {
    int bb = b - castBlocks;
    const float* W = (bb < 256) ? W1 : W2;
    unsigned short* Wt = (bb < 256) ? W1t : W2t;
    int nn = bb & 255, k = threadIdx.x;
    Wt[nn * 256 + k] = f2bf(W[k * 256 + nn]);
  }
}

// ------------------------- bf16 MFMA GEMM -------------------------
// C is written SLICE-MAJOR: C[s][row][32] with s = feat>>5 (8 slices of 32 feats, 64B each),
// slice pitch = Mpad*32 shorts. A is linear (sliceA=0) or slice-major (sliceA=1).
// Fused attention-logit epilogue (als/ald) from the LDS-staged tile (dense col layout).
__global__ __launch_bounds__(256) void k_gemm(const unsigned short* __restrict__ A,
                                              const unsigned short* __restrict__ Bt,
                                              unsigned short* __restrict__ C,
                                              const float* __restrict__ asrc,
                                              const float* __restrict__ adst,
                                              float* __restrict__ als,
                                              float* __restrict__ ald,
                                              int nRows, int multi, int Mpad, int sliceA){
  __shared__ __align__(16) unsigned short sh[8192];   // As = sh[0:4096], Bs = sh[4096:8192] (shorts)
  unsigned short* As = sh;
  unsigned short* Bs = sh + 4096;
  int tid = threadIdx.x;
  int lane = tid & 63, wave = tid >> 6;
  int rowBase = blockIdx.x * 128, colBase = blockIdx.y * 128;
  int wr = (wave & 1) * 64, wc = (wave >> 1) * 64;

  f32x4 acc[4][4] = {};
  int c0 = tid, c1 = tid + 256;
  int r0 = c0 >> 2, kc0 = (c0 & 3) * 8;
  int r1 = c1 >> 2, kc1 = (c1 & 3) * 8;
  int m0 = lane & 15, kq = (lane >> 4) * 8;

  size_t slicePitch = (size_t)Mpad * 32;
  for (int k0 = 0; k0 < 256; k0 += 32){
    const unsigned short* Ak = sliceA ? (A + (size_t)(k0 >> 5) * slicePitch) : (A + k0);
    size_t rstride = sliceA ? 32 : 256;
    gld_lds16(Ak + (size_t)(rowBase + r0) * rstride + kc0, (char*)As + c0 * 16);
    gld_lds16(Ak + (size_t)(rowBase + r1) * rstride + kc1, (char*)As + c1 * 16);
    gld_lds16(Bt + (size_t)(colBase + r0) * 256 + k0 + kc0, (char*)Bs + c0 * 16);
    gld_lds16(Bt + (size_t)(colBase + r1) * 256 + k0 + kc1, (char*)Bs + c1 * 16);
    __syncthreads();
    bf16x8 af[4], bfr[4];
    #pragma unroll
    for (int it = 0; it < 4; ++it)
      af[it] = *(const bf16x8*)(As + (wr + it * 16 + m0) * 32 + kq);
    #pragma unroll
    for (int jt = 0; jt < 4; ++jt)
      bfr[jt] = *(const bf16x8*)(Bs + (wc + jt * 16 + m0) * 32 + kq);
    #pragma unroll
    for (int it = 0; it < 4; ++it)
      #pragma unroll
      for (int jt = 0; jt < 4; ++jt)
        acc[it][jt] = __builtin_amdgcn_mfma_f32_16x16x32_bf16(af[it], bfr[jt], acc[it][jt], 0, 0, 0);
    __syncthreads();
  }
  // epilogue: repack C/D frags through LDS -> 16B slice-major stores + fused logit dots.
  int cq = lane >> 4, cm = lane & 15;
  int sg = tid & 7;                      // 8-short segment within a row
  float accS[4] = {0.f,0.f,0.f,0.f}, accD[4] = {0.f,0.f,0.f,0.f};
  #pragma unroll
  for (int p = 0; p < 2; ++p){
    if ((wave >> 1) == p){
      #pragma unroll
      for (int it = 0; it < 4; ++it)
        #pragma unroll
        for (int jt = 0; jt < 4; ++jt)
          #pragma unroll
          for (int r = 0; r < 4; ++r)
            sh[(wr + it * 16 + cq * 4 + r) * 64 + jt * 16 + cm] = f2bf(acc[it][jt][r]);
    }
    __syncthreads();
    int feat = colBase + p * 64 + sg * 8;
    const float* asl = asrc + feat;
    const float* adl = adst + feat;
    float as8[8], ad8[8];
    #pragma unroll
    for (int k = 0; k < 8; ++k){ as8[k] = asl[k]; ad8[k] = adl[k]; }
    size_t cSliceBase = (size_t)(feat >> 5) * slicePitch + (feat & 31);
    #pragma unroll
    for (int q = 0; q < 4; ++q){
      int id = tid + q * 256;            // 0..1023
      int r = id >> 3;                   // row 0..127
      u16x8 v = *(const u16x8*)(sh + r * 64 + sg * 8);
      *(u16x8*)(C + cSliceBase + (size_t)(rowBase + r) * 32) = v;
      float ps = 0.f, pd = 0.f;
      #pragma unroll
      for (int k = 0; k < 8; ++k){
        float hv = bf2f((unsigned short)v[k]);
        ps += hv * as8[k]; pd += hv * ad8[k];
      }
      if (multi){
        #pragma unroll
        for (int off = 4; off >= 1; off >>= 1){
          ps += __shfl_down(ps, off, 8);
          pd += __shfl_down(pd, off, 8);
        }
        if (sg == 0){
          int grow = rowBase + r;
          if (grow < nRows){
            int hp = (colBase >> 6) + p;      // head index (64 cols per head)
            als[(size_t)grow * 4 + hp] = ps;
            ald[(size_t)grow * 4 + hp] = pd;
          }
        }
      } else {
        accS[q] += ps; accD[q] += pd;
      }
    }
    __syncthreads();
  }
  if (!multi){
    #pragma unroll
    for (int q = 0; q < 4; ++q){
      float ps = accS[q], pd = accD[q];
      #pragma unroll
      for (int off = 4; off >= 1; off >>= 1){
        ps += __shfl_down(ps, off, 8);
        pd += __shfl_down(pd, off, 8);
      }
      if (sg == 0){
        int r = (tid + q * 256) >> 3;
        int grow = rowBase + r;
        if (grow < nRows){
          atomicAdd(&als[grow], ps);          // 2 contenders (block.y=0/1) -> deterministic
          atomicAdd(&ald[grow], pd);
        }
      }
    }
  }
}

// ------------------------- normalized edge weights, layer 1 (4 heads, head-major streams) -------------------------
__global__ __launch_bounds__(256) void k_alpha4(const float* __restrict__ als, const float* __restrict__ ald,
    const int* __restrict__ rowptr, const int* __restrict__ col,
    float* __restrict__ alpha, int Ep, int n){
  int wave = threadIdx.x >> 6, t = threadIdx.x & 63;
  int i = blockIdx.x * 4 + wave; if (i >= n) i = n - 1;
  int start = rowptr[i], deg = rowptr[i + 1] - start;
  float4 adv = *(const float4*)(ald + (size_t)i * 4);
  float4 sum = make_float4(0.f, 0.f, 0.f, 0.f);
  for (int j = t; j < deg; j += 64){
    int s = col[start + j];
    float4 a = *(const float4*)(als + (size_t)s * 4);
    sum.x += __expf(leaky(a.x + adv.x)); sum.y += __expf(leaky(a.y + adv.y));
    sum.z += __expf(leaky(a.z + adv.z)); sum.w += __expf(leaky(a.w + adv.w));
  }
  #pragma unroll
  for (int off = 32; off >= 1; off >>= 1) sum = make_float4(
      sum.x + __shfl_down(sum.x, off, 64), sum.y + __shfl_down(sum.y, off, 64),
      sum.z + __shfl_down(sum.z, off, 64), sum.w + __shfl_down(sum.w, off, 64));
  float4 d4 = bcast4(sum);
  float4 inv = make_float4(1.f/(d4.x+1e-16f), 1.f/(d4.y+1e-16f), 1.f/(d4.z+1e-16f), 1.f/(d4.w+1e-16f));
  for (int j = t; j < deg; j += 64){
    int s = col[start + j];
    float4 a = *(const float4*)(als + (size_t)s * 4);
    alpha[0*(size_t)Ep + start + j] = __expf(leaky(a.x + adv.x)) * inv.x;
    alpha[1*(size_t)Ep + start + j] = __expf(leaky(a.y + adv.y)) * inv.y;
    alpha[2*(size_t)Ep + start + j] = __expf(leaky(a.z + adv.z)) * inv.z;
    alpha[3*(size_t)Ep + start + j] = __expf(leaky(a.w + adv.w)) * inv.w;
  }
}

// ------------------------- normalized edge weights, layer 2 (1 head) -------------------------
__global__ __launch_bounds__(256) void k_alpha1h(const float* __restrict__ als, const float* __restrict__ ald,
    const int* __restrict__ rowptr, const int* __restrict__ col,
    float* __restrict__ alpha, int n){
  int wave = threadIdx.x >> 6, t = threadIdx.x & 63;
  int i = blockIdx.x * 4 + wave; if (i >= n) i = n - 1;
  int start = rowptr[i], deg = rowptr[i + 1] - start;
  float adv = ald[i];
  float sum = 0.f;
  for (int j = t; j < deg; j += 64) sum += __expf(leaky(als[col[start + j]] + adv));
  #pragma unroll
  for (int off = 32; off >= 1; off >>= 1) sum += __shfl_down(sum, off, 64);
  float inv = 1.f / (__shfl(sum, 0, 64) + 1e-16f);
  for (int j = t; j < deg; j += 64)
    alpha[start + j] = __expf(leaky(als[col[start + j]] + adv)) * inv;
}

// ------------------------- sliced gather, layer 1 -------------------------
// grid: bid = group*8 + s; slice s pinned to XCD s via wgid%8 round-robin.
// Per-XCD gathered working set = one contiguous H slice (Mpad*64B ~ 3.2MB < 4MB L2).
__global__ __launch_bounds__(256) void k_gat1(const unsigned short* __restrict__ Hsl,
    const float* __restrict__ alpha, int Ep,
    const int* __restrict__ rowptr, const int* __restrict__ col,
    const float* __restrict__ b, unsigned short* __restrict__ outSl, int n, int Mpad){
  int s = blockIdx.x & 7, grp = blockIdx.x >> 3;
  int wave = threadIdx.x >> 6, lane = threadIdx.x & 63;
  int i = grp * 4 + wave;
  if (i >= n) return;
  int start = rowptr[i], deg = rowptr[i + 1] - start;
  const float* al = alpha + (size_t)(s >> 1) * Ep + start;   // head = s/2 (64 feats/head)
  const unsigned short* Hs = Hsl + (size_t)s * Mpad * 32;
  int g4 = lane >> 4, l16 = lane & 15;
  float a0 = 0.f, a1 = 0.f;
  for (int j = g4; j < deg; j += 4){
    int src = __builtin_nontemporal_load(col + start + j);
    float aw = __builtin_nontemporal_load(al + j);
    unsigned int hv = *(const unsigned int*)(Hs + (size_t)src * 32 + l16 * 2);
    a0 += aw * bf2f((unsigned short)(hv & 0xffffu));
    a1 += aw * bf2f((unsigned short)(hv >> 16));
  }
  a0 += __shfl_xor(a0, 16); a0 += __shfl_xor(a0, 32);
  a1 += __shfl_xor(a1, 16); a1 += __shfl_xor(a1, 32);
  if (lane < 16){
    float2 bb = *(const float2*)(b + s * 32 + l16 * 2);
    float v0 = a0 + bb.x, v1 = a1 + bb.y;
    v0 = (v0 > 0.f) ? v0 : (__expf(v0) - 1.f);    // ELU
    v1 = (v1 > 0.f) ? v1 : (__expf(v1) - 1.f);
    unsigned int o = (unsigned int)f2bf(v0) | ((unsigned int)f2bf(v1) << 16);
    *(unsigned int*)(outSl + ((size_t)s * Mpad + i) * 32 + l16 * 2) = o;
  }
}

// ------------------------- sliced gather, layer 2 (fp32 out, standard row-major) -------------------------
__global__ __launch_bounds__(256) void k_gat2(const unsigned short* __restrict__ Hsl,
    const float* __restrict__ alpha,
    const int* __restrict__ rowptr, const int* __restrict__ col,
    const float* __restrict__ b, float* __restrict__ out, int n, int Mpad){
  int s = blockIdx.x & 7, grp = blockIdx.x >> 3;
  int wave = threadIdx.x >> 6, lane = threadIdx.x & 63;
  int i = grp * 4 + wave;
  if (i >= n) return;
  int start = rowptr[i], deg = rowptr[i + 1] - start;
  const float* al = alpha + start;
  const unsigned short* Hs = Hsl + (size_t)s * Mpad * 32;
  int g4 = lane >> 4, l16 = lane & 15;
  float a0 = 0.f, a1 = 0.f;
  for (int j = g4; j < deg; j += 4){
    int src = __builtin_nontemporal_load(col + start + j);
    float aw = __builtin_nontemporal_load(al + j);
    unsigned int hv = *(const unsigned int*)(Hs + (size_t)src * 32 + l16 * 2);
    a0 += aw * bf2f((unsigned short)(hv & 0xffffu));
    a1 += aw * bf2f((unsigned short)(hv >> 16));
  }
  a0 += __shfl_xor(a0, 16); a0 += __shfl_xor(a0, 32);
  a1 += __shfl_xor(a1, 16); a1 += __shfl_xor(a1, 32);
  if (lane < 16){
    float2 bb = *(const float2*)(b + s * 32 + l16 * 2);
    float2 o = make_float2(a0 + bb.x, a1 + bb.y);
    *(float2*)(out + (size_t)i * FDIM + s * 32 + l16 * 2) = o;
  }
}

// ------------------------- launch -------------------------
extern "C" void kernel_launch(void* const* d_in, const int* in_sizes, int n_in,
                              void* d_out, int out_size, void* d_ws, size_t ws_size,
                              hipStream_t stream){
  const float* x   = (const float*)d_in[0];
  const int*   ei  = (const int*)d_in[1];
  const float* W1  = (const float*)d_in[2];
  const float* as1 = (const float*)d_in[3];
  const float* ad1 = (const float*)d_in[4];
  const float* b1  = (const float*)d_in[5];
  const float* W2  = (const float*)d_in[6];
  const float* as2 = (const float*)d_in[7];
  const float* ad2 = (const float*)d_in[8];
  const float* b2  = (const float*)d_in[9];
  float* out = (float*)d_out;

  int n = in_sizes[0] / IN_DIM;     // 50000
  int E = in_sizes[1] / 2;          // 800000
  int Mpad = (n + 127) & ~127;      // 50048
  int Ep = E + n;                   // edges incl self loops
  const int* srcIdx = ei;
  const int* dstIdx = ei + E;

  char* ws = (char*)d_ws;
  size_t off = 0;
  auto alloc = [&](size_t bytes) -> void* {
    void* p = ws + off; off += (bytes + 255) & ~(size_t)255; return p;
  };
  unsigned short* bufA = (unsigned short*)alloc((size_t)Mpad * FDIM * 2);  // xb (linear), then out1 (slice-major)
  unsigned short* bufB = (unsigned short*)alloc((size_t)Mpad * FDIM * 2);  // H1 / H2 (slice-major)
  unsigned short* W1t  = (unsigned short*)alloc(256 * 256 * 2);
  unsigned short* W2t  = (unsigned short*)alloc(256 * 256 * 2);
  int*   tmp      = (int*)alloc((size_t)n * 4);
  int*   deg      = (int*)alloc((size_t)n * 4);
  int*   fill     = (int*)alloc((size_t)n * 4);
  int*   rowptr   = (int*)alloc((size_t)(n + 1) * 4);
  int*   partials = (int*)alloc(1024 * 4);
  int*   col      = (int*)alloc((size_t)Ep * 4);
  float* als1     = (float*)alloc((size_t)n * HEADS * 4);
  float* ald1     = (float*)alloc((size_t)n * HEADS * 4);
  float* als2     = (float*)alloc((size_t)n * 4);
  float* ald2     = (float*)alloc((size_t)n * 4);
  float* alpha1   = (float*)alloc((size_t)Ep * HEADS * 4);  // head-major [4][Ep]
  float* alpha2   = (float*)alloc((size_t)Ep * 4);
  (void)ws_size;

  int nb = (n + 255) / 256;
  // CSR build
  hipMemsetAsync(deg, 0, (size_t)n * 4, stream);
  hipMemsetAsync(fill, 0, (size_t)n * 4, stream);
  hipMemsetAsync(als2, 0, (size_t)n * 4, stream);   // layer-2 logits accumulated via atomicAdd
  hipMemsetAsync(ald2, 0, (size_t)n * 4, stream);
  k_hist<<<(E + 255) / 256, 256, 0, stream>>>(dstIdx, deg, E);
  k_scanA<<<nb, 256, 0, stream>>>(deg, tmp, partials, n);
  k_scanB<<<1, 1024, 0, stream>>>(partials, nb);
  k_scanC<<<nb, 256, 0, stream>>>(tmp, deg, partials, rowptr, n);
  k_fill<<<(E + n + 255) / 256, 256, 0, stream>>>(srcIdx, dstIdx, rowptr, fill, col, E, n);

  // fused cast + weight transposes
  int castBlocks = (Mpad * (FDIM / 4) + 255) / 256;
  k_castwt<<<castBlocks + 512, 256, 0, stream>>>(x, bufA, n, castBlocks, W1, W1t, W2, W2t);

  dim3 gg(Mpad / 128, FDIM / 128);
  int ga = (n + 3) / 4;
  int gGat = ((n + 3) / 4) * 8;     // groups x 8 slices
  // layer 1
  k_gemm<<<gg, 256, 0, stream>>>(bufA, W1t, bufB, as1, ad1, als1, ald1, n, 1, Mpad, 0);  // H1 slice-major + als1/ald1
  k_alpha4<<<ga, 256, 0, stream>>>(als1, ald1, rowptr, col, alpha1, Ep, n);
  k_gat1<<<gGat, 256, 0, stream>>>(bufB, alpha1, Ep, rowptr, col, b1, bufA, n, Mpad);    // out1 slice-major (ELU'd bf16)
  // layer 2
  k_gemm<<<gg, 256, 0, stream>>>(bufA, W2t, bufB, as2, ad2, als2, ald2, n, 0, Mpad, 1);  // H2 slice-major + als2/ald2
  k_alpha1h<<<ga, 256, 0, stream>>>(als2, ald2, rowptr, col, alpha2, n);
  k_gat2<<<gGat, 256, 0, stream>>>(bufB, alpha2, rowptr, col, b2, out, n, Mpad);
}

// Round 5
// 645.259 us; speedup vs baseline: 1.2408x; 1.2408x over previous
//
#include <hip/hip_runtime.h>
#include <math.h>

#define IN_DIM 256
#define FDIM 256      // HEADS*HID == OUT == 256
#define HEADS 4
#define NEG 0.2f
#define MAXD 96       // per-node staged edge cap; in-deg ~ Poisson(16)+1, P(>96) ~ 0

typedef __attribute__((ext_vector_type(8))) short bf16x8;
typedef __attribute__((ext_vector_type(8))) unsigned short u16x8;
typedef __attribute__((ext_vector_type(4))) float f32x4;

__device__ __forceinline__ float leaky(float x){ return x > 0.f ? x : NEG * x; }

__device__ __forceinline__ unsigned short f2bf(float f){
  unsigned int u = __float_as_uint(f);
  unsigned int r = u + 0x7fffu + ((u >> 16) & 1u);   // round-to-nearest-even
  return (unsigned short)(r >> 16);
}
__device__ __forceinline__ float bf2f(unsigned short s){
  return __uint_as_float(((unsigned int)s) << 16);
}

__device__ __forceinline__ float4 bcast4(float4 v){
  return make_float4(__shfl(v.x,0,64), __shfl(v.y,0,64), __shfl(v.z,0,64), __shfl(v.w,0,64));
}

__device__ __forceinline__ void gld_lds16(const void* g, void* l){
  __builtin_amdgcn_global_load_lds((const __attribute__((address_space(1))) unsigned int*)g,
                                   (__attribute__((address_space(3))) unsigned int*)l, 16, 0, 0);
}

// ------------------------- CSR build -------------------------
__global__ void k_hist(const int* __restrict__ dst, int* deg, int E){
  int e = blockIdx.x * blockDim.x + threadIdx.x;
  if (e < E) atomicAdd(&deg[dst[e]], 1);
}

__global__ void k_scanA(const int* __restrict__ deg, int* tmp, int* partials, int n){
  __shared__ int sm[256];
  int i = blockIdx.x * 256 + threadIdx.x;
  int v = (i < n) ? deg[i] + 1 : 0;     // +1: self loop
  sm[threadIdx.x] = v; __syncthreads();
  for (int off = 1; off < 256; off <<= 1){
    int x = (threadIdx.x >= off) ? sm[threadIdx.x - off] : 0;
    __syncthreads();
    sm[threadIdx.x] += x;
    __syncthreads();
  }
  if (i < n) tmp[i] = sm[threadIdx.x];            // inclusive within block
  if (threadIdx.x == 255) partials[blockIdx.x] = sm[255];
}

__global__ void k_scanB(int* partials, int nb){   // single block of 1024
  __shared__ int sm[1024];
  int t = threadIdx.x;
  int v = (t < nb) ? partials[t] : 0;
  sm[t] = v; __syncthreads();
  for (int off = 1; off < 1024; off <<= 1){
    int x = (t >= off) ? sm[t - off] : 0;
    __syncthreads();
    sm[t] += x;
    __syncthreads();
  }
  if (t < nb) partials[t] = sm[t] - v;            // exclusive
}

__global__ void k_scanC(const int* __restrict__ tmp, const int* __restrict__ deg,
                        const int* __restrict__ partials, int* rowptr, int n){
  int i = blockIdx.x * blockDim.x + threadIdx.x;
  if (i < n){
    int incl = tmp[i] + partials[i >> 8];
    rowptr[i] = incl - (deg[i] + 1);
    if (i == n - 1) rowptr[n] = incl;             // total = E + n
  }
}

__global__ void k_fill(const int* __restrict__ src, const int* __restrict__ dst,
                       const int* __restrict__ rowptr, int* fill, int* col, int E, int n){
  int e = blockIdx.x * blockDim.x + threadIdx.x;
  if (e < E + n){
    int s, d;
    if (e < E){ s = src[e]; d = dst[e]; } else { s = d = e - E; }
    int pos = atomicAdd(&fill[d], 1);
    col[rowptr[d] + pos] = s;
  }
}

// ------------------------- fused: x fp32->bf16 cast (padded) + W1/W2 transpose-cast -------------------------
__global__ void k_castwt(const float* __restrict__ x, unsigned short* __restrict__ xb, int M, int castBlocks,
                         const float* __restrict__ W1, unsigned short* __restrict__ W1t,
                         const float* __restrict__ W2, unsigned short* __restrict__ W2t){
  int b = blockIdx.x;
  if (b < castBlocks){
    int idx = b * 256 + threadIdx.x;   // one ushort4 group per thread
    int row = idx >> 6;
    float4 v = make_float4(0.f, 0.f, 0.f, 0.f);
    if (row < M) v = *(const float4*)(x + (size_t)idx * 4);
    ushort4 o;
    o.x = f2bf(v.x); o.y = f2bf(v.y); o.z = f2bf(v.z); o.w = f2bf(v.w);
    *(ushort4*)(xb + (size_t)idx * 4) = o;
  } else {
    int bb = b - castBlocks;
    const float* W = (bb < 256) ? W1 : W2;
    unsigned short* Wt = (bb < 256) ? W1t : W2t;
    int nn = bb & 255, k = threadIdx.x;
    Wt[nn * 256 + k] = f2bf(W[k * 256 + nn]);
  }
}

// ------------------------- bf16 MFMA GEMM -------------------------
// C is written SLICE-MAJOR: C[s][row][32] with s = feat>>5 (8 slices of 32 feats, 64B each),
// slice pitch = Mpad*32 shorts. A is linear (sliceA=0) or slice-major (sliceA=1).
// Fused attention-logit epilogue (als/ald) from the LDS-staged tile (dense col layout).
__global__ __launch_bounds__(256) void k_gemm(const unsigned short* __restrict__ A,
                                              const unsigned short* __restrict__ Bt,
                                              unsigned short* __restrict__ C,
                                              const float* __restrict__ asrc,
                                              const float* __restrict__ adst,
                                              float* __restrict__ als,
                                              float* __restrict__ ald,
                                              int nRows, int multi, int Mpad, int sliceA){
  __shared__ __align__(16) unsigned short sh[8192];   // As = sh[0:4096], Bs = sh[4096:8192] (shorts)
  unsigned short* As = sh;
  unsigned short* Bs = sh + 4096;
  int tid = threadIdx.x;
  int lane = tid & 63, wave = tid >> 6;
  int rowBase = blockIdx.x * 128, colBase = blockIdx.y * 128;
  int wr = (wave & 1) * 64, wc = (wave >> 1) * 64;

  f32x4 acc[4][4] = {};
  int c0 = tid, c1 = tid + 256;
  int r0 = c0 >> 2, kc0 = (c0 & 3) * 8;
  int r1 = c1 >> 2, kc1 = (c1 & 3) * 8;
  int m0 = lane & 15, kq = (lane >> 4) * 8;

  size_t slicePitch = (size_t)Mpad * 32;
  for (int k0 = 0; k0 < 256; k0 += 32){
    const unsigned short* Ak = sliceA ? (A + (size_t)(k0 >> 5) * slicePitch) : (A + k0);
    size_t rstride = sliceA ? 32 : 256;
    gld_lds16(Ak + (size_t)(rowBase + r0) * rstride + kc0, (char*)As + c0 * 16);
    gld_lds16(Ak + (size_t)(rowBase + r1) * rstride + kc1, (char*)As + c1 * 16);
    gld_lds16(Bt + (size_t)(colBase + r0) * 256 + k0 + kc0, (char*)Bs + c0 * 16);
    gld_lds16(Bt + (size_t)(colBase + r1) * 256 + k0 + kc1, (char*)Bs + c1 * 16);
    __syncthreads();
    bf16x8 af[4], bfr[4];
    #pragma unroll
    for (int it = 0; it < 4; ++it)
      af[it] = *(const bf16x8*)(As + (wr + it * 16 + m0) * 32 + kq);
    #pragma unroll
    for (int jt = 0; jt < 4; ++jt)
      bfr[jt] = *(const bf16x8*)(Bs + (wc + jt * 16 + m0) * 32 + kq);
    #pragma unroll
    for (int it = 0; it < 4; ++it)
      #pragma unroll
      for (int jt = 0; jt < 4; ++jt)
        acc[it][jt] = __builtin_amdgcn_mfma_f32_16x16x32_bf16(af[it], bfr[jt], acc[it][jt], 0, 0, 0);
    __syncthreads();
  }
  // epilogue: repack C/D frags through LDS -> 16B slice-major stores + fused logit dots.
  int cq = lane >> 4, cm = lane & 15;
  int sg = tid & 7;                      // 8-short segment within a row
  float accS[4] = {0.f,0.f,0.f,0.f}, accD[4] = {0.f,0.f,0.f,0.f};
  #pragma unroll
  for (int p = 0; p < 2; ++p){
    if ((wave >> 1) == p){
      #pragma unroll
      for (int it = 0; it < 4; ++it)
        #pragma unroll
        for (int jt = 0; jt < 4; ++jt)
          #pragma unroll
          for (int r = 0; r < 4; ++r)
            sh[(wr + it * 16 + cq * 4 + r) * 64 + jt * 16 + cm] = f2bf(acc[it][jt][r]);
    }
    __syncthreads();
    int feat = colBase + p * 64 + sg * 8;
    const float* asl = asrc + feat;
    const float* adl = adst + feat;
    float as8[8], ad8[8];
    #pragma unroll
    for (int k = 0; k < 8; ++k){ as8[k] = asl[k]; ad8[k] = adl[k]; }
    size_t cSliceBase = (size_t)(feat >> 5) * slicePitch + (feat & 31);
    #pragma unroll
    for (int q = 0; q < 4; ++q){
      int id = tid + q * 256;            // 0..1023
      int r = id >> 3;                   // row 0..127
      u16x8 v = *(const u16x8*)(sh + r * 64 + sg * 8);
      *(u16x8*)(C + cSliceBase + (size_t)(rowBase + r) * 32) = v;
      float ps = 0.f, pd = 0.f;
      #pragma unroll
      for (int k = 0; k < 8; ++k){
        float hv = bf2f((unsigned short)v[k]);
        ps += hv * as8[k]; pd += hv * ad8[k];
      }
      if (multi){
        #pragma unroll
        for (int off = 4; off >= 1; off >>= 1){
          ps += __shfl_down(ps, off, 8);
          pd += __shfl_down(pd, off, 8);
        }
        if (sg == 0){
          int grow = rowBase + r;
          if (grow < nRows){
            int hp = (colBase >> 6) + p;      // head index (64 cols per head)
            als[(size_t)grow * 4 + hp] = ps;
            ald[(size_t)grow * 4 + hp] = pd;
          }
        }
      } else {
        accS[q] += ps; accD[q] += pd;
      }
    }
    __syncthreads();
  }
  if (!multi){
    #pragma unroll
    for (int q = 0; q < 4; ++q){
      float ps = accS[q], pd = accD[q];
      #pragma unroll
      for (int off = 4; off >= 1; off >>= 1){
        ps += __shfl_down(ps, off, 8);
        pd += __shfl_down(pd, off, 8);
      }
      if (sg == 0){
        int r = (tid + q * 256) >> 3;
        int grow = rowBase + r;
        if (grow < nRows){
          atomicAdd(&als[grow], ps);          // 2 contenders (block.y=0/1) -> deterministic
          atomicAdd(&ald[grow], pd);
        }
      }
    }
  }
}

// ------------------------- normalized edge weights, layer 1 (4 heads, head-major streams) -------------------------
__global__ __launch_bounds__(256) void k_alpha4(const float* __restrict__ als, const float* __restrict__ ald,
    const int* __restrict__ rowptr, const int* __restrict__ col,
    float* __restrict__ alpha, int Ep, int n){
  int wave = threadIdx.x >> 6, t = threadIdx.x & 63;
  int i = blockIdx.x * 4 + wave; if (i >= n) i = n - 1;
  int start = rowptr[i], deg = rowptr[i + 1] - start;
  float4 adv = *(const float4*)(ald + (size_t)i * 4);
  float4 sum = make_float4(0.f, 0.f, 0.f, 0.f);
  for (int j = t; j < deg; j += 64){
    int s = col[start + j];
    float4 a = *(const float4*)(als + (size_t)s * 4);
    sum.x += __expf(leaky(a.x + adv.x)); sum.y += __expf(leaky(a.y + adv.y));
    sum.z += __expf(leaky(a.z + adv.z)); sum.w += __expf(leaky(a.w + adv.w));
  }
  #pragma unroll
  for (int off = 32; off >= 1; off >>= 1) sum = make_float4(
      sum.x + __shfl_down(sum.x, off, 64), sum.y + __shfl_down(sum.y, off, 64),
      sum.z + __shfl_down(sum.z, off, 64), sum.w + __shfl_down(sum.w, off, 64));
  float4 d4 = bcast4(sum);
  float4 inv = make_float4(1.f/(d4.x+1e-16f), 1.f/(d4.y+1e-16f), 1.f/(d4.z+1e-16f), 1.f/(d4.w+1e-16f));
  for (int j = t; j < deg; j += 64){
    int s = col[start + j];
    float4 a = *(const float4*)(als + (size_t)s * 4);
    alpha[0*(size_t)Ep + start + j] = __expf(leaky(a.x + adv.x)) * inv.x;
    alpha[1*(size_t)Ep + start + j] = __expf(leaky(a.y + adv.y)) * inv.y;
    alpha[2*(size_t)Ep + start + j] = __expf(leaky(a.z + adv.z)) * inv.z;
    alpha[3*(size_t)Ep + start + j] = __expf(leaky(a.w + adv.w)) * inv.w;
  }
}

// ------------------------- normalized edge weights, layer 2 (1 head) -------------------------
__global__ __launch_bounds__(256) void k_alpha1h(const float* __restrict__ als, const float* __restrict__ ald,
    const int* __restrict__ rowptr, const int* __restrict__ col,
    float* __restrict__ alpha, int n){
  int wave = threadIdx.x >> 6, t = threadIdx.x & 63;
  int i = blockIdx.x * 4 + wave; if (i >= n) i = n - 1;
  int start = rowptr[i], deg = rowptr[i + 1] - start;
  float adv = ald[i];
  float sum = 0.f;
  for (int j = t; j < deg; j += 64) sum += __expf(leaky(als[col[start + j]] + adv));
  #pragma unroll
  for (int off = 32; off >= 1; off >>= 1) sum += __shfl_down(sum, off, 64);
  float inv = 1.f / (__shfl(sum, 0, 64) + 1e-16f);
  for (int j = t; j < deg; j += 64)
    alpha[start + j] = __expf(leaky(als[col[start + j]] + adv)) * inv;
}

// ------------------------- sliced gather, layer 1 (LDS-staged col/alpha) -------------------------
// grid: bid = group*8 + s; slice s pinned to XCD s via wgid%8 round-robin.
// Per-XCD gathered working set = one contiguous H slice (Mpad*64B ~ 3.2MB < 4MB L2).
// Each wave stages its node's col+alpha in LDS with coalesced nt loads (protects L2 slice),
// then 16-lane groups gather 4B/lane from the L2-resident slice (independent iters, ~200cyc).
__global__ __launch_bounds__(256) void k_gat1(const unsigned short* __restrict__ Hsl,
    const float* __restrict__ alpha, int Ep,
    const int* __restrict__ rowptr, const int* __restrict__ col,
    const float* __restrict__ b, unsigned short* __restrict__ outSl, int n, int Mpad){
  __shared__ int   colS[4][MAXD];
  __shared__ float wS[4][MAXD];
  int s = blockIdx.x & 7, grp = blockIdx.x >> 3;
  int wave = threadIdx.x >> 6, lane = threadIdx.x & 63;
  int i = grp * 4 + wave; if (i >= n) i = n - 1;   // dup nodes write identical data
  int start = rowptr[i], deg = rowptr[i + 1] - start;
  const float* al = alpha + (size_t)(s >> 1) * Ep + start;   // head = s/2 (64 feats/head)
  bool staged = (deg <= MAXD);
  if (staged){
    for (int j = lane; j < deg; j += 64){           // coalesced wave-wide staging
      colS[wave][j] = __builtin_nontemporal_load(col + start + j);
      wS[wave][j]   = __builtin_nontemporal_load(al + j);
    }
  }
  // no __syncthreads: each wave consumes only its own LDS rows (compiler inserts lgkmcnt)
  const unsigned short* Hs = Hsl + (size_t)s * Mpad * 32;
  int g = lane >> 4, l16 = lane & 15;
  float a0 = 0.f, a1 = 0.f;
  if (staged){
    for (int j = g; j < deg; j += 4){
      int src = colS[wave][j];
      float w = wS[wave][j];
      unsigned int hv = *(const unsigned int*)(Hs + (size_t)src * 32 + l16 * 2);
      a0 += w * bf2f((unsigned short)(hv & 0xffffu));
      a1 += w * bf2f((unsigned short)(hv >> 16));
    }
  } else {
    for (int j = g; j < deg; j += 4){
      int src = col[start + j];
      float w = al[j];
      unsigned int hv = *(const unsigned int*)(Hs + (size_t)src * 32 + l16 * 2);
      a0 += w * bf2f((unsigned short)(hv & 0xffffu));
      a1 += w * bf2f((unsigned short)(hv >> 16));
    }
  }
  a0 += __shfl_xor(a0, 16); a0 += __shfl_xor(a0, 32);
  a1 += __shfl_xor(a1, 16); a1 += __shfl_xor(a1, 32);
  if (lane < 16){
    float2 bb = *(const float2*)(b + s * 32 + l16 * 2);
    float v0 = a0 + bb.x, v1 = a1 + bb.y;
    v0 = (v0 > 0.f) ? v0 : (__expf(v0) - 1.f);    // ELU
    v1 = (v1 > 0.f) ? v1 : (__expf(v1) - 1.f);
    unsigned int o = (unsigned int)f2bf(v0) | ((unsigned int)f2bf(v1) << 16);
    *(unsigned int*)(outSl + ((size_t)s * Mpad + i) * 32 + l16 * 2) = o;
  }
}

// ------------------------- sliced gather, layer 2 (LDS-staged, fp32 out row-major) -------------------------
__global__ __launch_bounds__(256) void k_gat2(const unsigned short* __restrict__ Hsl,
    const float* __restrict__ alpha,
    const int* __restrict__ rowptr, const int* __restrict__ col,
    const float* __restrict__ b, float* __restrict__ out, int n, int Mpad){
  __shared__ int   colS[4][MAXD];
  __shared__ float wS[4][MAXD];
  int s = blockIdx.x & 7, grp = blockIdx.x >> 3;
  int wave = threadIdx.x >> 6, lane = threadIdx.x & 63;
  int i = grp * 4 + wave; if (i >= n) i = n - 1;
  int start = rowptr[i], deg = rowptr[i + 1] - start;
  const float* al = alpha + start;
  bool staged = (deg <= MAXD);
  if (staged){
    for (int j = lane; j < deg; j += 64){
      colS[wave][j] = __builtin_nontemporal_load(col + start + j);
      wS[wave][j]   = __builtin_nontemporal_load(al + j);
    }
  }
  const unsigned short* Hs = Hsl + (size_t)s * Mpad * 32;
  int g = lane >> 4, l16 = lane & 15;
  float a0 = 0.f, a1 = 0.f;
  if (staged){
    for (int j = g; j < deg; j += 4){
      int src = colS[wave][j];
      float w = wS[wave][j];
      unsigned int hv = *(const unsigned int*)(Hs + (size_t)src * 32 + l16 * 2);
      a0 += w * bf2f((unsigned short)(hv & 0xffffu));
      a1 += w * bf2f((unsigned short)(hv >> 16));
    }
  } else {
    for (int j = g; j < deg; j += 4){
      int src = col[start + j];
      float w = al[j];
      unsigned int hv = *(const unsigned int*)(Hs + (size_t)src * 32 + l16 * 2);
      a0 += w * bf2f((unsigned short)(hv & 0xffffu));
      a1 += w * bf2f((unsigned short)(hv >> 16));
    }
  }
  a0 += __shfl_xor(a0, 16); a0 += __shfl_xor(a0, 32);
  a1 += __shfl_xor(a1, 16); a1 += __shfl_xor(a1, 32);
  if (lane < 16){
    float2 bb = *(const float2*)(b + s * 32 + l16 * 2);
    float2 o = make_float2(a0 + bb.x, a1 + bb.y);
    *(float2*)(out + (size_t)i * FDIM + s * 32 + l16 * 2) = o;
  }
}

// ------------------------- launch -------------------------
extern "C" void kernel_launch(void* const* d_in, const int* in_sizes, int n_in,
                              void* d_out, int out_size, void* d_ws, size_t ws_size,
                              hipStream_t stream){
  const float* x   = (const float*)d_in[0];
  const int*   ei  = (const int*)d_in[1];
  const float* W1  = (const float*)d_in[2];
  const float* as1 = (const float*)d_in[3];
  const float* ad1 = (const float*)d_in[4];
  const float* b1  = (const float*)d_in[5];
  const float* W2  = (const float*)d_in[6];
  const float* as2 = (const float*)d_in[7];
  const float* ad2 = (const float*)d_in[8];
  const float* b2  = (const float*)d_in[9];
  float* out = (float*)d_out;

  int n = in_sizes[0] / IN_DIM;     // 50000
  int E = in_sizes[1] / 2;          // 800000
  int Mpad = (n + 127) & ~127;      // 50048
  int Ep = E + n;                   // edges incl self loops
  const int* srcIdx = ei;
  const int* dstIdx = ei + E;

  char* ws = (char*)d_ws;
  size_t off = 0;
  auto alloc = [&](size_t bytes) -> void* {
    void* p = ws + off; off += (bytes + 255) & ~(size_t)255; return p;
  };
  unsigned short* bufA = (unsigned short*)alloc((size_t)Mpad * FDIM * 2);  // xb (linear), then out1 (slice-major)
  unsigned short* bufB = (unsigned short*)alloc((size_t)Mpad * FDIM * 2);  // H1 / H2 (slice-major)
  unsigned short* W1t  = (unsigned short*)alloc(256 * 256 * 2);
  unsigned short* W2t  = (unsigned short*)alloc(256 * 256 * 2);
  int*   tmp      = (int*)alloc((size_t)n * 4);
  int*   deg      = (int*)alloc((size_t)n * 4);
  int*   fill     = (int*)alloc((size_t)n * 4);
  int*   rowptr   = (int*)alloc((size_t)(n + 1) * 4);
  int*   partials = (int*)alloc(1024 * 4);
  int*   col      = (int*)alloc((size_t)Ep * 4);
  float* als1     = (float*)alloc((size_t)n * HEADS * 4);
  float* ald1     = (float*)alloc((size_t)n * HEADS * 4);
  float* als2     = (float*)alloc((size_t)n * 4);
  float* ald2     = (float*)alloc((size_t)n * 4);
  float* alpha1   = (float*)alloc((size_t)Ep * HEADS * 4);  // head-major [4][Ep]
  float* alpha2   = (float*)alloc((size_t)Ep * 4);
  (void)ws_size;

  int nb = (n + 255) / 256;
  // CSR build
  hipMemsetAsync(deg, 0, (size_t)n * 4, stream);
  hipMemsetAsync(fill, 0, (size_t)n * 4, stream);
  hipMemsetAsync(als2, 0, (size_t)n * 4, stream);   // layer-2 logits accumulated via atomicAdd
  hipMemsetAsync(ald2, 0, (size_t)n * 4, stream);
  k_hist<<<(E + 255) / 256, 256, 0, stream>>>(dstIdx, deg, E);
  k_scanA<<<nb, 256, 0, stream>>>(deg, tmp, partials, n);
  k_scanB<<<1, 1024, 0, stream>>>(partials, nb);
  k_scanC<<<nb, 256, 0, stream>>>(tmp, deg, partials, rowptr, n);
  k_fill<<<(E + n + 255) / 256, 256, 0, stream>>>(srcIdx, dstIdx, rowptr, fill, col, E, n);

  // fused cast + weight transposes
  int castBlocks = (Mpad * (FDIM / 4) + 255) / 256;
  k_castwt<<<castBlocks + 512, 256, 0, stream>>>(x, bufA, n, castBlocks, W1, W1t, W2, W2t);

  dim3 gg(Mpad / 128, FDIM / 128);
  int ga = (n + 3) / 4;
  int gGat = ((n + 3) / 4) * 8;     // groups x 8 slices
  // layer 1
  k_gemm<<<gg, 256, 0, stream>>>(bufA, W1t, bufB, as1, ad1, als1, ald1, n, 1, Mpad, 0);  // H1 slice-major + als1/ald1
  k_alpha4<<<ga, 256, 0, stream>>>(als1, ald1, rowptr, col, alpha1, Ep, n);
  k_gat1<<<gGat, 256, 0, stream>>>(bufB, alpha1, Ep, rowptr, col, b1, bufA, n, Mpad);    // out1 slice-major (ELU'd bf16)
  // layer 2
  k_gemm<<<gg, 256, 0, stream>>>(bufA, W2t, bufB, as2, ad2, als2, ald2, n, 0, Mpad, 1);  // H2 slice-major + als2/ald2
  k_alpha1h<<<ga, 256, 0, stream>>>(als2, ald2, rowptr, col, alpha2, n);
  k_gat2<<<gGat, 256, 0, stream>>>(bufB, alpha2, rowptr, col, b2, out, n, Mpad);
}

// Round 6
// 583.856 us; speedup vs baseline: 1.3713x; 1.1052x over previous
//
#include <hip/hip_runtime.h>
#include <math.h>

#define IN_DIM 256
#define FDIM 256      // HEADS*HID == OUT == 256
#define HEADS 4
#define NEG 0.2f
#define CH 48         // gather chunk (edges per wave in flight); deg ~ Poisson(16)+1

typedef __attribute__((ext_vector_type(8))) short bf16x8;
typedef __attribute__((ext_vector_type(8))) unsigned short u16x8;
typedef __attribute__((ext_vector_type(4))) float f32x4;

__device__ __forceinline__ float leaky(float x){ return x > 0.f ? x : NEG * x; }

__device__ __forceinline__ unsigned short f2bf(float f){
  unsigned int u = __float_as_uint(f);
  unsigned int r = u + 0x7fffu + ((u >> 16) & 1u);   // round-to-nearest-even
  return (unsigned short)(r >> 16);
}
__device__ __forceinline__ float bf2f(unsigned short s){
  return __uint_as_float(((unsigned int)s) << 16);
}

__device__ __forceinline__ float4 bcast4(float4 v){
  return make_float4(__shfl(v.x,0,64), __shfl(v.y,0,64), __shfl(v.z,0,64), __shfl(v.w,0,64));
}

__device__ __forceinline__ void gld_lds16(const void* g, void* l){
  __builtin_amdgcn_global_load_lds((const __attribute__((address_space(1))) unsigned int*)g,
                                   (__attribute__((address_space(3))) unsigned int*)l, 16, 0, 0);
}
__device__ __forceinline__ void gld_lds4(const void* g, void* l){
  __builtin_amdgcn_global_load_lds((const __attribute__((address_space(1))) unsigned int*)g,
                                   (__attribute__((address_space(3))) unsigned int*)l, 4, 0, 0);
}

// ------------------------- CSR build -------------------------
__global__ void k_hist(const int* __restrict__ dst, int* deg, int E){
  int e = blockIdx.x * blockDim.x + threadIdx.x;
  if (e < E) atomicAdd(&deg[dst[e]], 1);
}

__global__ void k_scanA(const int* __restrict__ deg, int* tmp, int* partials, int n){
  __shared__ int sm[256];
  int i = blockIdx.x * 256 + threadIdx.x;
  int v = (i < n) ? deg[i] + 1 : 0;     // +1: self loop
  sm[threadIdx.x] = v; __syncthreads();
  for (int off = 1; off < 256; off <<= 1){
    int x = (threadIdx.x >= off) ? sm[threadIdx.x - off] : 0;
    __syncthreads();
    sm[threadIdx.x] += x;
    __syncthreads();
  }
  if (i < n) tmp[i] = sm[threadIdx.x];            // inclusive within block
  if (threadIdx.x == 255) partials[blockIdx.x] = sm[255];
}

__global__ void k_scanB(int* partials, int nb){   // single block of 1024
  __shared__ int sm[1024];
  int t = threadIdx.x;
  int v = (t < nb) ? partials[t] : 0;
  sm[t] = v; __syncthreads();
  for (int off = 1; off < 1024; off <<= 1){
    int x = (t >= off) ? sm[t - off] : 0;
    __syncthreads();
    sm[t] += x;
    __syncthreads();
  }
  if (t < nb) partials[t] = sm[t] - v;            // exclusive
}

__global__ void k_scanC(const int* __restrict__ tmp, const int* __restrict__ deg,
                        const int* __restrict__ partials, int* rowptr, int n){
  int i = blockIdx.x * blockDim.x + threadIdx.x;
  if (i < n){
    int incl = tmp[i] + partials[i >> 8];
    rowptr[i] = incl - (deg[i] + 1);
    if (i == n - 1) rowptr[n] = incl;             // total = E + n
  }
}

__global__ void k_fill(const int* __restrict__ src, const int* __restrict__ dst,
                       const int* __restrict__ rowptr, int* fill, int* col, int E, int n){
  int e = blockIdx.x * blockDim.x + threadIdx.x;
  if (e < E + n){
    int s, d;
    if (e < E){ s = src[e]; d = dst[e]; } else { s = d = e - E; }
    int pos = atomicAdd(&fill[d], 1);
    col[rowptr[d] + pos] = s;
  }
}

// ------------------------- fused: x fp32->bf16 cast (padded) + W1/W2 transpose-cast -------------------------
__global__ void k_castwt(const float* __restrict__ x, unsigned short* __restrict__ xb, int M, int castBlocks,
                         const float* __restrict__ W1, unsigned short* __restrict__ W1t,
                         const float* __restrict__ W2, unsigned short* __restrict__ W2t){
  int b = blockIdx.x;
  if (b < castBlocks){
    int idx = b * 256 + threadIdx.x;   // one ushort4 group per thread
    int row = idx >> 6;
    float4 v = make_float4(0.f, 0.f, 0.f, 0.f);
    if (row < M) v = *(const float4*)(x + (size_t)idx * 4);
    ushort4 o;
    o.x = f2bf(v.x); o.y = f2bf(v.y); o.z = f2bf(v.z); o.w = f2bf(v.w);
    *(ushort4*)(xb + (size_t)idx * 4) = o;
  } else {
    int bb = b - castBlocks;
    const float* W = (bb < 256) ? W1 : W2;
    unsigned short* Wt = (bb < 256) ? W1t : W2t;
    int nn = bb & 255, k = threadIdx.x;
    Wt[nn * 256 + k] = f2bf(W[k * 256 + nn]);
  }
}

// ------------------------- bf16 MFMA GEMM -------------------------
// C is written SLICE-MAJOR: C[s][row][32] with s = feat>>5 (8 slices of 32 feats, 64B each),
// slice pitch = Mpad*32 shorts. A is linear (sliceA=0) or slice-major (sliceA=1).
// Fused attention-logit epilogue (als/ald) from the LDS-staged tile (dense col layout).
__global__ __launch_bounds__(256) void k_gemm(const unsigned short* __restrict__ A,
                                              const unsigned short* __restrict__ Bt,
                                              unsigned short* __restrict__ C,
                                              const float* __restrict__ asrc,
                                              const float* __restrict__ adst,
                                              float* __restrict__ als,
                                              float* __restrict__ ald,
                                              int nRows, int multi, int Mpad, int sliceA){
  __shared__ __align__(16) unsigned short sh[8192];   // As = sh[0:4096], Bs = sh[4096:8192] (shorts)
  unsigned short* As = sh;
  unsigned short* Bs = sh + 4096;
  int tid = threadIdx.x;
  int lane = tid & 63, wave = tid >> 6;
  int rowBase = blockIdx.x * 128, colBase = blockIdx.y * 128;
  int wr = (wave & 1) * 64, wc = (wave >> 1) * 64;

  f32x4 acc[4][4] = {};
  int c0 = tid, c1 = tid + 256;
  int r0 = c0 >> 2, kc0 = (c0 & 3) * 8;
  int r1 = c1 >> 2, kc1 = (c1 & 3) * 8;
  int m0 = lane & 15, kq = (lane >> 4) * 8;

  size_t slicePitch = (size_t)Mpad * 32;
  for (int k0 = 0; k0 < 256; k0 += 32){
    const unsigned short* Ak = sliceA ? (A + (size_t)(k0 >> 5) * slicePitch) : (A + k0);
    size_t rstride = sliceA ? 32 : 256;
    gld_lds16(Ak + (size_t)(rowBase + r0) * rstride + kc0, (char*)As + c0 * 16);
    gld_lds16(Ak + (size_t)(rowBase + r1) * rstride + kc1, (char*)As + c1 * 16);
    gld_lds16(Bt + (size_t)(colBase + r0) * 256 + k0 + kc0, (char*)Bs + c0 * 16);
    gld_lds16(Bt + (size_t)(colBase + r1) * 256 + k0 + kc1, (char*)Bs + c1 * 16);
    __syncthreads();
    bf16x8 af[4], bfr[4];
    #pragma unroll
    for (int it = 0; it < 4; ++it)
      af[it] = *(const bf16x8*)(As + (wr + it * 16 + m0) * 32 + kq);
    #pragma unroll
    for (int jt = 0; jt < 4; ++jt)
      bfr[jt] = *(const bf16x8*)(Bs + (wc + jt * 16 + m0) * 32 + kq);
    #pragma unroll
    for (int it = 0; it < 4; ++it)
      #pragma unroll
      for (int jt = 0; jt < 4; ++jt)
        acc[it][jt] = __builtin_amdgcn_mfma_f32_16x16x32_bf16(af[it], bfr[jt], acc[it][jt], 0, 0, 0);
    __syncthreads();
  }
  // epilogue: repack C/D frags through LDS -> 16B slice-major stores + fused logit dots.
  int cq = lane >> 4, cm = lane & 15;
  int sg = tid & 7;                      // 8-short segment within a row
  float accS[4] = {0.f,0.f,0.f,0.f}, accD[4] = {0.f,0.f,0.f,0.f};
  #pragma unroll
  for (int p = 0; p < 2; ++p){
    if ((wave >> 1) == p){
      #pragma unroll
      for (int it = 0; it < 4; ++it)
        #pragma unroll
        for (int jt = 0; jt < 4; ++jt)
          #pragma unroll
          for (int r = 0; r < 4; ++r)
            sh[(wr + it * 16 + cq * 4 + r) * 64 + jt * 16 + cm] = f2bf(acc[it][jt][r]);
    }
    __syncthreads();
    int feat = colBase + p * 64 + sg * 8;
    const float* asl = asrc + feat;
    const float* adl = adst + feat;
    float as8[8], ad8[8];
    #pragma unroll
    for (int k = 0; k < 8; ++k){ as8[k] = asl[k]; ad8[k] = adl[k]; }
    size_t cSliceBase = (size_t)(feat >> 5) * slicePitch + (feat & 31);
    #pragma unroll
    for (int q = 0; q < 4; ++q){
      int id = tid + q * 256;            // 0..1023
      int r = id >> 3;                   // row 0..127
      u16x8 v = *(const u16x8*)(sh + r * 64 + sg * 8);
      *(u16x8*)(C + cSliceBase + (size_t)(rowBase + r) * 32) = v;
      float ps = 0.f, pd = 0.f;
      #pragma unroll
      for (int k = 0; k < 8; ++k){
        float hv = bf2f((unsigned short)v[k]);
        ps += hv * as8[k]; pd += hv * ad8[k];
      }
      if (multi){
        #pragma unroll
        for (int off = 4; off >= 1; off >>= 1){
          ps += __shfl_down(ps, off, 8);
          pd += __shfl_down(pd, off, 8);
        }
        if (sg == 0){
          int grow = rowBase + r;
          if (grow < nRows){
            int hp = (colBase >> 6) + p;      // head index (64 cols per head)
            als[(size_t)grow * 4 + hp] = ps;
            ald[(size_t)grow * 4 + hp] = pd;
          }
        }
      } else {
        accS[q] += ps; accD[q] += pd;
      }
    }
    __syncthreads();
  }
  if (!multi){
    #pragma unroll
    for (int q = 0; q < 4; ++q){
      float ps = accS[q], pd = accD[q];
      #pragma unroll
      for (int off = 4; off >= 1; off >>= 1){
        ps += __shfl_down(ps, off, 8);
        pd += __shfl_down(pd, off, 8);
      }
      if (sg == 0){
        int r = (tid + q * 256) >> 3;
        int grow = rowBase + r;
        if (grow < nRows){
          atomicAdd(&als[grow], ps);          // 2 contenders (block.y=0/1) -> deterministic
          atomicAdd(&ald[grow], pd);
        }
      }
    }
  }
}

// ------------------------- normalized edge weights, layer 1 (single-pass for deg<=64) -------------------------
__global__ __launch_bounds__(256) void k_alpha4(const float* __restrict__ als, const float* __restrict__ ald,
    const int* __restrict__ rowptr, const int* __restrict__ col,
    float* __restrict__ alpha, int Ep, int n){
  int wave = threadIdx.x >> 6, t = threadIdx.x & 63;
  int i = blockIdx.x * 4 + wave; if (i >= n) i = n - 1;
  int start = rowptr[i], deg = rowptr[i + 1] - start;
  float4 adv = *(const float4*)(ald + (size_t)i * 4);
  if (deg <= 64){
    float4 w = make_float4(0.f, 0.f, 0.f, 0.f);
    if (t < deg){
      int s = col[start + t];
      float4 a = *(const float4*)(als + (size_t)s * 4);
      w = make_float4(__expf(leaky(a.x + adv.x)), __expf(leaky(a.y + adv.y)),
                      __expf(leaky(a.z + adv.z)), __expf(leaky(a.w + adv.w)));
    }
    float4 sum = w;
    #pragma unroll
    for (int off = 32; off >= 1; off >>= 1) sum = make_float4(
        sum.x + __shfl_down(sum.x, off, 64), sum.y + __shfl_down(sum.y, off, 64),
        sum.z + __shfl_down(sum.z, off, 64), sum.w + __shfl_down(sum.w, off, 64));
    float4 d4 = bcast4(sum);
    if (t < deg){
      alpha[0*(size_t)Ep + start + t] = w.x / (d4.x + 1e-16f);
      alpha[1*(size_t)Ep + start + t] = w.y / (d4.y + 1e-16f);
      alpha[2*(size_t)Ep + start + t] = w.z / (d4.z + 1e-16f);
      alpha[3*(size_t)Ep + start + t] = w.w / (d4.w + 1e-16f);
    }
    return;
  }
  float4 sum = make_float4(0.f, 0.f, 0.f, 0.f);
  for (int j = t; j < deg; j += 64){
    int s = col[start + j];
    float4 a = *(const float4*)(als + (size_t)s * 4);
    sum.x += __expf(leaky(a.x + adv.x)); sum.y += __expf(leaky(a.y + adv.y));
    sum.z += __expf(leaky(a.z + adv.z)); sum.w += __expf(leaky(a.w + adv.w));
  }
  #pragma unroll
  for (int off = 32; off >= 1; off >>= 1) sum = make_float4(
      sum.x + __shfl_down(sum.x, off, 64), sum.y + __shfl_down(sum.y, off, 64),
      sum.z + __shfl_down(sum.z, off, 64), sum.w + __shfl_down(sum.w, off, 64));
  float4 d4 = bcast4(sum);
  float4 inv = make_float4(1.f/(d4.x+1e-16f), 1.f/(d4.y+1e-16f), 1.f/(d4.z+1e-16f), 1.f/(d4.w+1e-16f));
  for (int j = t; j < deg; j += 64){
    int s = col[start + j];
    float4 a = *(const float4*)(als + (size_t)s * 4);
    alpha[0*(size_t)Ep + start + j] = __expf(leaky(a.x + adv.x)) * inv.x;
    alpha[1*(size_t)Ep + start + j] = __expf(leaky(a.y + adv.y)) * inv.y;
    alpha[2*(size_t)Ep + start + j] = __expf(leaky(a.z + adv.z)) * inv.z;
    alpha[3*(size_t)Ep + start + j] = __expf(leaky(a.w + adv.w)) * inv.w;
  }
}

// ------------------------- normalized edge weights, layer 2 (single-pass for deg<=64) -------------------------
__global__ __launch_bounds__(256) void k_alpha1h(const float* __restrict__ als, const float* __restrict__ ald,
    const int* __restrict__ rowptr, const int* __restrict__ col,
    float* __restrict__ alpha, int n){
  int wave = threadIdx.x >> 6, t = threadIdx.x & 63;
  int i = blockIdx.x * 4 + wave; if (i >= n) i = n - 1;
  int start = rowptr[i], deg = rowptr[i + 1] - start;
  float adv = ald[i];
  if (deg <= 64){
    float w = 0.f;
    if (t < deg) w = __expf(leaky(als[col[start + t]] + adv));
    float sum = w;
    #pragma unroll
    for (int off = 32; off >= 1; off >>= 1) sum += __shfl_down(sum, off, 64);
    float d = __shfl(sum, 0, 64);
    if (t < deg) alpha[start + t] = w / (d + 1e-16f);
    return;
  }
  float sum = 0.f;
  for (int j = t; j < deg; j += 64) sum += __expf(leaky(als[col[start + j]] + adv));
  #pragma unroll
  for (int off = 32; off >= 1; off >>= 1) sum += __shfl_down(sum, off, 64);
  float inv = 1.f / (__shfl(sum, 0, 64) + 1e-16f);
  for (int j = t; j < deg; j += 64)
    alpha[start + j] = __expf(leaky(als[col[start + j]] + adv)) * inv;
}

// ------------------------- sliced gather via global_load_lds DMA (fire-and-forget) -------------------------
// grid: bid = group*8 + s; slice s pinned to XCD s (wgid%8 round-robin); per-XCD working set =
// one contiguous H slice (~3.2MB < 4MB L2). Per wave (node,slice): stage col+alpha chunk, issue
// ceil(cnt/4) gather DMAs back-to-back (per-lane global addr, linear LDS dest, 4 edge-rows/instr),
// ONE vmcnt(0) drain, then LDS accumulate (2-way bank aliasing = free). Latency paid once/chunk.
__global__ __launch_bounds__(256) void k_gat1(const unsigned short* __restrict__ Hsl,
    const float* __restrict__ alpha, int Ep,
    const int* __restrict__ rowptr, const int* __restrict__ col,
    const float* __restrict__ b, unsigned short* __restrict__ outSl, int n, int Mpad){
  __shared__ __align__(16) int   colS[4][CH];
  __shared__ __align__(16) float wS[4][CH];
  __shared__ __align__(16) unsigned short gbuf[4][CH * 32];   // CH rows x 64B per wave
  int s = blockIdx.x & 7, grp = blockIdx.x >> 3;
  int wave = threadIdx.x >> 6, lane = threadIdx.x & 63;
  int i = grp * 4 + wave; if (i >= n) i = n - 1;   // dup nodes write identical data
  int start = rowptr[i], deg = rowptr[i + 1] - start;
  const float* al = alpha + (size_t)(s >> 1) * Ep + start;   // head = s/2 (64 feats/head)
  const unsigned short* Hs = Hsl + (size_t)s * Mpad * 32;
  int eg = lane >> 4, l16 = lane & 15;
  float a0 = 0.f, a1 = 0.f;
  for (int c0 = 0; c0 < deg; c0 += CH){
    int cnt = deg - c0; if (cnt > CH) cnt = CH;
    if (lane < cnt){                                 // coalesced chunk staging
      colS[wave][lane] = __builtin_nontemporal_load(col + start + c0 + lane);
      wS[wave][lane]   = __builtin_nontemporal_load(al + c0 + lane);
    }
    int ngath = (cnt + 3) >> 2;
    for (int c = 0; c < ngath; ++c){                 // fire-and-forget: 4 edges / instr
      int e = c * 4 + eg;
      int ec = (e < cnt) ? e : cnt - 1;              // clamp (dup read, not accumulated)
      int src = colS[wave][ec];
      gld_lds4(Hs + (size_t)src * 32 + l16 * 2, &gbuf[wave][c * 128]);
    }
    asm volatile("s_waitcnt vmcnt(0)" ::: "memory");
    __builtin_amdgcn_sched_barrier(0);
    for (int k = eg; k < cnt; k += 4){               // LDS accumulate
      unsigned int hv = *(const unsigned int*)(&gbuf[wave][k * 32 + l16 * 2]);
      float w = wS[wave][k];
      a0 += w * bf2f((unsigned short)(hv & 0xffffu));
      a1 += w * bf2f((unsigned short)(hv >> 16));
    }
    if (c0 + CH < deg){                              // rare multi-chunk: reads done before re-DMA
      asm volatile("s_waitcnt lgkmcnt(0)" ::: "memory");
      __builtin_amdgcn_sched_barrier(0);
    }
  }
  a0 += __shfl_xor(a0, 16); a0 += __shfl_xor(a0, 32);
  a1 += __shfl_xor(a1, 16); a1 += __shfl_xor(a1, 32);
  if (lane < 16){
    float2 bb = *(const float2*)(b + s * 32 + l16 * 2);
    float v0 = a0 + bb.x, v1 = a1 + bb.y;
    v0 = (v0 > 0.f) ? v0 : (__expf(v0) - 1.f);    // ELU
    v1 = (v1 > 0.f) ? v1 : (__expf(v1) - 1.f);
    unsigned int o = (unsigned int)f2bf(v0) | ((unsigned int)f2bf(v1) << 16);
    *(unsigned int*)(outSl + ((size_t)s * Mpad + i) * 32 + l16 * 2) = o;
  }
}

// ------------------------- sliced gather, layer 2 (DMA, fp32 out row-major) -------------------------
__global__ __launch_bounds__(256) void k_gat2(const unsigned short* __restrict__ Hsl,
    const float* __restrict__ alpha,
    const int* __restrict__ rowptr, const int* __restrict__ col,
    const float* __restrict__ b, float* __restrict__ out, int n, int Mpad){
  __shared__ __align__(16) int   colS[4][CH];
  __shared__ __align__(16) float wS[4][CH];
  __shared__ __align__(16) unsigned short gbuf[4][CH * 32];
  int s = blockIdx.x & 7, grp = blockIdx.x >> 3;
  int wave = threadIdx.x >> 6, lane = threadIdx.x & 63;
  int i = grp * 4 + wave; if (i >= n) i = n - 1;
  int start = rowptr[i], deg = rowptr[i + 1] - start;
  const float* al = alpha + start;
  const unsigned short* Hs = Hsl + (size_t)s * Mpad * 32;
  int eg = lane >> 4, l16 = lane & 15;
  float a0 = 0.f, a1 = 0.f;
  for (int c0 = 0; c0 < deg; c0 += CH){
    int cnt = deg - c0; if (cnt > CH) cnt = CH;
    if (lane < cnt){
      colS[wave][lane] = __builtin_nontemporal_load(col + start + c0 + lane);
      wS[wave][lane]   = __builtin_nontemporal_load(al + c0 + lane);
    }
    int ngath = (cnt + 3) >> 2;
    for (int c = 0; c < ngath; ++c){
      int e = c * 4 + eg;
      int ec = (e < cnt) ? e : cnt - 1;
      int src = colS[wave][ec];
      gld_lds4(Hs + (size_t)src * 32 + l16 * 2, &gbuf[wave][c * 128]);
    }
    asm volatile("s_waitcnt vmcnt(0)" ::: "memory");
    __builtin_amdgcn_sched_barrier(0);
    for (int k = eg; k < cnt; k += 4){
      unsigned int hv = *(const unsigned int*)(&gbuf[wave][k * 32 + l16 * 2]);
      float w = wS[wave][k];
      a0 += w * bf2f((unsigned short)(hv & 0xffffu));
      a1 += w * bf2f((unsigned short)(hv >> 16));
    }
    if (c0 + CH < deg){
      asm volatile("s_waitcnt lgkmcnt(0)" ::: "memory");
      __builtin_amdgcn_sched_barrier(0);
    }
  }
  a0 += __shfl_xor(a0, 16); a0 += __shfl_xor(a0, 32);
  a1 += __shfl_xor(a1, 16); a1 += __shfl_xor(a1, 32);
  if (lane < 16){
    float2 bb = *(const float2*)(b + s * 32 + l16 * 2);
    float2 o = make_float2(a0 + bb.x, a1 + bb.y);
    *(float2*)(out + (size_t)i * FDIM + s * 32 + l16 * 2) = o;
  }
}

// ------------------------- launch -------------------------
extern "C" void kernel_launch(void* const* d_in, const int* in_sizes, int n_in,
                              void* d_out, int out_size, void* d_ws, size_t ws_size,
                              hipStream_t stream){
  const float* x   = (const float*)d_in[0];
  const int*   ei  = (const int*)d_in[1];
  const float* W1  = (const float*)d_in[2];
  const float* as1 = (const float*)d_in[3];
  const float* ad1 = (const float*)d_in[4];
  const float* b1  = (const float*)d_in[5];
  const float* W2  = (const float*)d_in[6];
  const float* as2 = (const float*)d_in[7];
  const float* ad2 = (const float*)d_in[8];
  const float* b2  = (const float*)d_in[9];
  float* out = (float*)d_out;

  int n = in_sizes[0] / IN_DIM;     // 50000
  int E = in_sizes[1] / 2;          // 800000
  int Mpad = (n + 127) & ~127;      // 50048
  int Ep = E + n;                   // edges incl self loops
  const int* srcIdx = ei;
  const int* dstIdx = ei + E;

  char* ws = (char*)d_ws;
  size_t off = 0;
  auto alloc = [&](size_t bytes) -> void* {
    void* p = ws + off; off += (bytes + 255) & ~(size_t)255; return p;
  };
  unsigned short* bufA = (unsigned short*)alloc((size_t)Mpad * FDIM * 2);  // xb (linear), then out1 (slice-major)
  unsigned short* bufB = (unsigned short*)alloc((size_t)Mpad * FDIM * 2);  // H1 / H2 (slice-major)
  unsigned short* W1t  = (unsigned short*)alloc(256 * 256 * 2);
  unsigned short* W2t  = (unsigned short*)alloc(256 * 256 * 2);
  int*   tmp      = (int*)alloc((size_t)n * 4);
  int*   deg      = (int*)alloc((size_t)n * 4);
  int*   fill     = (int*)alloc((size_t)n * 4);
  int*   rowptr   = (int*)alloc((size_t)(n + 1) * 4);
  int*   partials = (int*)alloc(1024 * 4);
  int*   col      = (int*)alloc((size_t)Ep * 4);
  float* als1     = (float*)alloc((size_t)n * HEADS * 4);
  float* ald1     = (float*)alloc((size_t)n * HEADS * 4);
  float* als2     = (float*)alloc((size_t)n * 4);
  float* ald2     = (float*)alloc((size_t)n * 4);
  float* alpha1   = (float*)alloc((size_t)Ep * HEADS * 4);  // head-major [4][Ep]
  float* alpha2   = (float*)alloc((size_t)Ep * 4);
  (void)ws_size;

  int nb = (n + 255) / 256;
  // CSR build
  hipMemsetAsync(deg, 0, (size_t)n * 4, stream);
  hipMemsetAsync(fill, 0, (size_t)n * 4, stream);
  hipMemsetAsync(als2, 0, (size_t)n * 4, stream);   // layer-2 logits accumulated via atomicAdd
  hipMemsetAsync(ald2, 0, (size_t)n * 4, stream);
  k_hist<<<(E + 255) / 256, 256, 0, stream>>>(dstIdx, deg, E);
  k_scanA<<<nb, 256, 0, stream>>>(deg, tmp, partials, n);
  k_scanB<<<1, 1024, 0, stream>>>(partials, nb);
  k_scanC<<<nb, 256, 0, stream>>>(tmp, deg, partials, rowptr, n);
  k_fill<<<(E + n + 255) / 256, 256, 0, stream>>>(srcIdx, dstIdx, rowptr, fill, col, E, n);

  // fused cast + weight transposes
  int castBlocks = (Mpad * (FDIM / 4) + 255) / 256;
  k_castwt<<<castBlocks + 512, 256, 0, stream>>>(x, bufA, n, castBlocks, W1, W1t, W2, W2t);

  dim3 gg(Mpad / 128, FDIM / 128);
  int ga = (n + 3) / 4;
  int gGat = ((n + 3) / 4) * 8;     // groups x 8 slices
  // layer 1
  k_gemm<<<gg, 256, 0, stream>>>(bufA, W1t, bufB, as1, ad1, als1, ald1, n, 1, Mpad, 0);  // H1 slice-major + als1/ald1
  k_alpha4<<<ga, 256, 0, stream>>>(als1, ald1, rowptr, col, alpha1, Ep, n);
  k_gat1<<<gGat, 256, 0, stream>>>(bufB, alpha1, Ep, rowptr, col, b1, bufA, n, Mpad);    // out1 slice-major (ELU'd bf16)
  // layer 2
  k_gemm<<<gg, 256, 0, stream>>>(bufA, W2t, bufB, as2, ad2, als2, ald2, n, 0, Mpad, 1);  // H2 slice-major + als2/ald2
  k_alpha1h<<<ga, 256, 0, stream>>>(als2, ald2, rowptr, col, alpha2, n);
  k_gat2<<<gGat, 256, 0, stream>>>(bufB, alpha2, rowptr, col, b2, out, n, Mpad);
}

// Round 7
// 413.414 us; speedup vs baseline: 1.9366x; 1.4123x over previous
//
#include <hip/hip_runtime.h>
#include <math.h>

#define IN_DIM 256
#define FDIM 256      // HEADS*HID == OUT == 256
#define HEADS 4
#define NEG 0.2f
#define MAXD 96       // per-node staged edge cap; in-deg ~ Poisson(16)+1, P(>96) ~ 0

typedef __attribute__((ext_vector_type(8))) short bf16x8;
typedef __attribute__((ext_vector_type(8))) unsigned short u16x8;
typedef __attribute__((ext_vector_type(4))) float f32x4;

__device__ __forceinline__ float leaky(float x){ return x > 0.f ? x : NEG * x; }

__device__ __forceinline__ unsigned short f2bf(float f){
  unsigned int u = __float_as_uint(f);
  unsigned int r = u + 0x7fffu + ((u >> 16) & 1u);   // round-to-nearest-even
  return (unsigned short)(r >> 16);
}
__device__ __forceinline__ float bf2f(unsigned short s){
  return __uint_as_float(((unsigned int)s) << 16);
}

__device__ __forceinline__ float4 bcast4(float4 v){
  return make_float4(__shfl(v.x,0,64), __shfl(v.y,0,64), __shfl(v.z,0,64), __shfl(v.w,0,64));
}
__device__ __forceinline__ float comp4(float4 v, int h){
  return h==0 ? v.x : h==1 ? v.y : h==2 ? v.z : v.w;
}

__device__ __forceinline__ void gld_lds16(const void* g, void* l){
  __builtin_amdgcn_global_load_lds((const __attribute__((address_space(1))) unsigned int*)g,
                                   (__attribute__((address_space(3))) unsigned int*)l, 16, 0, 0);
}

// ------------------------- CSR build -------------------------
__global__ void k_hist(const int* __restrict__ dst, int* deg, int E){
  int e = blockIdx.x * blockDim.x + threadIdx.x;
  if (e < E) atomicAdd(&deg[dst[e]], 1);
}

__global__ void k_scanA(const int* __restrict__ deg, int* tmp, int* partials, int n){
  __shared__ int sm[256];
  int i = blockIdx.x * 256 + threadIdx.x;
  int v = (i < n) ? deg[i] + 1 : 0;     // +1: self loop
  sm[threadIdx.x] = v; __syncthreads();
  for (int off = 1; off < 256; off <<= 1){
    int x = (threadIdx.x >= off) ? sm[threadIdx.x - off] : 0;
    __syncthreads();
    sm[threadIdx.x] += x;
    __syncthreads();
  }
  if (i < n) tmp[i] = sm[threadIdx.x];            // inclusive within block
  if (threadIdx.x == 255) partials[blockIdx.x] = sm[255];
}

__global__ void k_scanB(int* partials, int nb){   // single block of 1024
  __shared__ int sm[1024];
  int t = threadIdx.x;
  int v = (t < nb) ? partials[t] : 0;
  sm[t] = v; __syncthreads();
  for (int off = 1; off < 1024; off <<= 1){
    int x = (t >= off) ? sm[t - off] : 0;
    __syncthreads();
    sm[t] += x;
    __syncthreads();
  }
  if (t < nb) partials[t] = sm[t] - v;            // exclusive
}

__global__ void k_scanC(const int* __restrict__ tmp, const int* __restrict__ deg,
                        const int* __restrict__ partials, int* rowptr, int n){
  int i = blockIdx.x * blockDim.x + threadIdx.x;
  if (i < n){
    int incl = tmp[i] + partials[i >> 8];
    rowptr[i] = incl - (deg[i] + 1);
    if (i == n - 1) rowptr[n] = incl;             // total = E + n
  }
}

__global__ void k_fill(const int* __restrict__ src, const int* __restrict__ dst,
                       const int* __restrict__ rowptr, int* fill, int* col, int E, int n){
  int e = blockIdx.x * blockDim.x + threadIdx.x;
  if (e < E + n){
    int s, d;
    if (e < E){ s = src[e]; d = dst[e]; } else { s = d = e - E; }
    int pos = atomicAdd(&fill[d], 1);
    col[rowptr[d] + pos] = s;
  }
}

// ------------------------- fused: x fp32->bf16 cast (padded) + W1/W2 transpose-cast -------------------------
__global__ void k_castwt(const float* __restrict__ x, unsigned short* __restrict__ xb, int M, int castBlocks,
                         const float* __restrict__ W1, unsigned short* __restrict__ W1t,
                         const float* __restrict__ W2, unsigned short* __restrict__ W2t){
  int b = blockIdx.x;
  if (b < castBlocks){
    int idx = b * 256 + threadIdx.x;   // one ushort4 group per thread
    int row = idx >> 6;
    float4 v = make_float4(0.f, 0.f, 0.f, 0.f);
    if (row < M) v = *(const float4*)(x + (size_t)idx * 4);
    ushort4 o;
    o.x = f2bf(v.x); o.y = f2bf(v.y); o.z = f2bf(v.z); o.w = f2bf(v.w);
    *(ushort4*)(xb + (size_t)idx * 4) = o;
  } else {
    int bb = b - castBlocks;
    const float* W = (bb < 256) ? W1 : W2;
    unsigned short* Wt = (bb < 256) ? W1t : W2t;
    int nn = bb & 255, k = threadIdx.x;
    Wt[nn * 256 + k] = f2bf(W[k * 256 + nn]);
  }
}

// ------------------------- bf16 MFMA GEMM: C[M,256] = A[M,256] @ Bt[256,256]^T -------------------------
// Fused attention-logit epilogue: als/ald dot products computed from the LDS-staged bf16 C tile.
// multi=1 (layer1, HEADS=4): each p-round's 64 cols == one complete head -> direct store als[row*4+h].
// multi=0 (layer2, 1 head, 256 dims): per-block 128-col partials -> one atomicAdd per (row, block.y).
__global__ __launch_bounds__(256) void k_gemm(const unsigned short* __restrict__ A,
                                              const unsigned short* __restrict__ Bt,
                                              unsigned short* __restrict__ C,
                                              const float* __restrict__ asrc,
                                              const float* __restrict__ adst,
                                              float* __restrict__ als,
                                              float* __restrict__ ald,
                                              int nRows, int multi){
  __shared__ __align__(16) unsigned short sh[8192];   // As = sh[0:4096], Bs = sh[4096:8192] (shorts)
  unsigned short* As = sh;
  unsigned short* Bs = sh + 4096;
  int tid = threadIdx.x;
  int lane = tid & 63, wave = tid >> 6;
  int rowBase = blockIdx.x * 128, colBase = blockIdx.y * 128;
  int wr = (wave & 1) * 64, wc = (wave >> 1) * 64;

  f32x4 acc[4][4] = {};
  int c0 = tid, c1 = tid + 256;
  int r0 = c0 >> 2, kc0 = (c0 & 3) * 8;
  int r1 = c1 >> 2, kc1 = (c1 & 3) * 8;
  int m0 = lane & 15, kq = (lane >> 4) * 8;

  for (int k0 = 0; k0 < 256; k0 += 32){
    gld_lds16(A  + (size_t)(rowBase + r0) * 256 + k0 + kc0, (char*)As + c0 * 16);
    gld_lds16(A  + (size_t)(rowBase + r1) * 256 + k0 + kc1, (char*)As + c1 * 16);
    gld_lds16(Bt + (size_t)(colBase + r0) * 256 + k0 + kc0, (char*)Bs + c0 * 16);
    gld_lds16(Bt + (size_t)(colBase + r1) * 256 + k0 + kc1, (char*)Bs + c1 * 16);
    __syncthreads();
    bf16x8 af[4], bfr[4];
    #pragma unroll
    for (int it = 0; it < 4; ++it)
      af[it] = *(const bf16x8*)(As + (wr + it * 16 + m0) * 32 + kq);
    #pragma unroll
    for (int jt = 0; jt < 4; ++jt)
      bfr[jt] = *(const bf16x8*)(Bs + (wc + jt * 16 + m0) * 32 + kq);
    #pragma unroll
    for (int it = 0; it < 4; ++it)
      #pragma unroll
      for (int jt = 0; jt < 4; ++jt)
        acc[it][jt] = __builtin_amdgcn_mfma_f32_16x16x32_bf16(af[it], bfr[jt], acc[it][jt], 0, 0, 0);
    __syncthreads();
  }
  // epilogue: repack C/D frags (col=lane&15, row=(lane>>4)*4+reg) through LDS -> 16B stores,
  // plus fused attention-logit partial dots against asrc/adst.
  int cq = lane >> 4, cm = lane & 15;
  int sg = tid & 7;                      // 8-short segment within a row (same for all q)
  float accS[4] = {0.f,0.f,0.f,0.f}, accD[4] = {0.f,0.f,0.f,0.f};
  #pragma unroll
  for (int p = 0; p < 2; ++p){
    if ((wave >> 1) == p){
      #pragma unroll
      for (int it = 0; it < 4; ++it)
        #pragma unroll
        for (int jt = 0; jt < 4; ++jt)
          #pragma unroll
          for (int r = 0; r < 4; ++r)
            sh[(wr + it * 16 + cq * 4 + r) * 64 + jt * 16 + cm] = f2bf(acc[it][jt][r]);
    }
    __syncthreads();
    // att-vector slice for this thread's segment (uniform across q-rounds)
    const float* asl = asrc + colBase + p * 64 + sg * 8;
    const float* adl = adst + colBase + p * 64 + sg * 8;
    float as8[8], ad8[8];
    #pragma unroll
    for (int k = 0; k < 8; ++k){ as8[k] = asl[k]; ad8[k] = adl[k]; }
    // 128 rows x 8 segments of 8 shorts (16B) = 1024 segments; 256 threads x 4 rounds
    #pragma unroll
    for (int q = 0; q < 4; ++q){
      int id = tid + q * 256;            // 0..1023
      int r = id >> 3;                   // row 0..127
      u16x8 v = *(const u16x8*)(sh + r * 64 + sg * 8);
      *(u16x8*)(C + (size_t)(rowBase + r) * 256 + colBase + p * 64 + sg * 8) = v;
      float ps = 0.f, pd = 0.f;
      #pragma unroll
      for (int k = 0; k < 8; ++k){
        float hv = bf2f((unsigned short)v[k]);
        ps += hv * as8[k]; pd += hv * ad8[k];
      }
      if (multi){
        // reduce the 8 segment-threads of this row (consecutive lanes within a wave)
        #pragma unroll
        for (int off = 4; off >= 1; off >>= 1){
          ps += __shfl_down(ps, off, 8);
          pd += __shfl_down(pd, off, 8);
        }
        if (sg == 0){
          int grow = rowBase + r;
          if (grow < nRows){
            int hp = (colBase >> 6) + p;      // head index (64 cols per head)
            als[(size_t)grow * 4 + hp] = ps;
            ald[(size_t)grow * 4 + hp] = pd;
          }
        }
      } else {
        accS[q] += ps; accD[q] += pd;
      }
    }
    __syncthreads();
  }
  if (!multi){
    #pragma unroll
    for (int q = 0; q < 4; ++q){
      float ps = accS[q], pd = accD[q];
      #pragma unroll
      for (int off = 4; off >= 1; off >>= 1){
        ps += __shfl_down(ps, off, 8);
        pd += __shfl_down(pd, off, 8);
      }
      if (sg == 0){
        int r = (tid + q * 256) >> 3;
        int grow = rowBase + r;
        if (grow < nRows){
          atomicAdd(&als[grow], ps);          // 2 contenders (block.y=0/1) -> deterministic
          atomicAdd(&ald[grow], pd);
        }
      }
    }
  }
}

// ------------------------- layer-1 aggregation: 4 nodes/block, wave per node -------------------------
// softmax without max-subtraction (logits ~ +-3 here; mathematically identical)
// phase C is 4-deep unrolled: 4 independent 16B gathers in flight per lane (latency hiding).
__global__ __launch_bounds__(256) void k_agg1(const unsigned short* __restrict__ Hb,
    const float* __restrict__ als, const float* __restrict__ ald,
    const int* __restrict__ rowptr, const int* __restrict__ col,
    const float* __restrict__ b, unsigned short* __restrict__ outb, int n){
  __shared__ __align__(16) int   colS[4][MAXD];
  __shared__ __align__(16) float wS[4][MAXD][4];
  int wave = threadIdx.x >> 6, t = threadIdx.x & 63;
  int i = blockIdx.x * 4 + wave; if (i >= n) i = n - 1;
  int start = rowptr[i];
  int deg = rowptr[i + 1] - start;
  float4 adv = *(const float4*)(ald + (size_t)i * 4);
  bool staged = (deg <= MAXD);

  // phase A: stage col + softmax weights, accumulate per-head sums
  float4 ls = make_float4(0.f, 0.f, 0.f, 0.f);
  if (staged){
    for (int j = t; j < deg; j += 64){
      int s = col[start + j];
      colS[wave][j] = s;
      float4 a = *(const float4*)(als + (size_t)s * 4);
      float4 w = make_float4(__expf(leaky(a.x + adv.x)), __expf(leaky(a.y + adv.y)),
                             __expf(leaky(a.z + adv.z)), __expf(leaky(a.w + adv.w)));
      *(float4*)(&wS[wave][j][0]) = w;
      ls.x += w.x; ls.y += w.y; ls.z += w.z; ls.w += w.w;
    }
  } else {
    for (int j = t; j < deg; j += 64){
      int s = col[start + j];
      float4 a = *(const float4*)(als + (size_t)s * 4);
      ls.x += __expf(leaky(a.x + adv.x)); ls.y += __expf(leaky(a.y + adv.y));
      ls.z += __expf(leaky(a.z + adv.z)); ls.w += __expf(leaky(a.w + adv.w));
    }
  }
  #pragma unroll
  for (int off = 32; off >= 1; off >>= 1) ls = make_float4(
      ls.x + __shfl_down(ls.x, off, 64), ls.y + __shfl_down(ls.y, off, 64),
      ls.z + __shfl_down(ls.z, off, 64), ls.w + __shfl_down(ls.w, off, 64));
  float4 d4 = bcast4(ls);
  __syncthreads();

  // phase C: half-wave per edge, 8 feats/lane (16B loads), 4-deep edge unroll
  int e2 = t >> 5, l32 = t & 31;
  int h = l32 >> 3, f = l32 * 8;
  float inv = 1.f / (comp4(d4, h) + 1e-16f);
  const unsigned short* Hrow = Hb + f;
  float a0[8] = {0,0,0,0,0,0,0,0}, a1[8] = {0,0,0,0,0,0,0,0};
  float a2[8] = {0,0,0,0,0,0,0,0}, a3[8] = {0,0,0,0,0,0,0,0};
  if (staged){
    int j = 0;
    for (; j + 7 < deg; j += 8){
      int j0 = j + e2, j1 = j + 2 + e2, j2 = j + 4 + e2, j3 = j + 6 + e2;
      int s0 = colS[wave][j0], s1 = colS[wave][j1], s2 = colS[wave][j2], s3 = colS[wave][j3];
      float w0 = wS[wave][j0][h], w1 = wS[wave][j1][h], w2 = wS[wave][j2][h], w3 = wS[wave][j3][h];
      u16x8 h0 = *(const u16x8*)(Hrow + (size_t)s0 * FDIM);
      u16x8 h1 = *(const u16x8*)(Hrow + (size_t)s1 * FDIM);
      u16x8 h2 = *(const u16x8*)(Hrow + (size_t)s2 * FDIM);
      u16x8 h3 = *(const u16x8*)(Hrow + (size_t)s3 * FDIM);
      #pragma unroll
      for (int k = 0; k < 8; ++k){
        a0[k] += bf2f(h0[k]) * w0; a1[k] += bf2f(h1[k]) * w1;
        a2[k] += bf2f(h2[k]) * w2; a3[k] += bf2f(h3[k]) * w3;
      }
    }
    for (; j + 3 < deg; j += 4){
      int j0 = j + e2, j1 = j + 2 + e2;
      int s0 = colS[wave][j0], s1 = colS[wave][j1];
      float w0 = wS[wave][j0][h], w1 = wS[wave][j1][h];
      u16x8 h0 = *(const u16x8*)(Hrow + (size_t)s0 * FDIM);
      u16x8 h1 = *(const u16x8*)(Hrow + (size_t)s1 * FDIM);
      #pragma unroll
      for (int k = 0; k < 8; ++k){ a0[k] += bf2f(h0[k]) * w0; a1[k] += bf2f(h1[k]) * w1; }
    }
    for (; j < deg; j += 2){
      int jj = j + e2;
      if (jj < deg){
        int s = colS[wave][jj]; float w = wS[wave][jj][h];
        u16x8 hh = *(const u16x8*)(Hrow + (size_t)s * FDIM);
        #pragma unroll
        for (int k = 0; k < 8; ++k) a0[k] += bf2f(hh[k]) * w;
      }
    }
  } else {
    float adh = comp4(adv, h);
    for (int j = e2; j < deg; j += 2){
      int s = col[start + j];
      float w = __expf(leaky(als[(size_t)s * 4 + h] + adh));
      u16x8 hh = *(const u16x8*)(Hrow + (size_t)s * FDIM);
      #pragma unroll
      for (int k = 0; k < 8; ++k) a0[k] += bf2f(hh[k]) * w;
    }
  }
  float r[8];
  #pragma unroll
  for (int k = 0; k < 8; ++k){
    r[k] = (a0[k] + a1[k]) + (a2[k] + a3[k]);
    r[k] += __shfl_down(r[k], 32, 64);
  }
  if (t < 32){
    float4 bA = *(const float4*)(b + f);
    float4 bB = *(const float4*)(b + f + 4);
    float bb[8] = {bA.x, bA.y, bA.z, bA.w, bB.x, bB.y, bB.z, bB.w};
    u16x8 o;
    #pragma unroll
    for (int k = 0; k < 8; ++k){
      float v = r[k] * inv + bb[k];
      v = (v > 0.f) ? v : (__expf(v) - 1.f);    // ELU
      o[k] = f2bf(v);
    }
    *(u16x8*)(outb + (size_t)i * FDIM + f) = o;
  }
}

// ------------------------- layer-2 aggregation: 4 nodes/block, wave per node, fp32 out -------------------------
__global__ __launch_bounds__(256) void k_agg2(const unsigned short* __restrict__ Hb,
    const float* __restrict__ als, const float* __restrict__ ald,
    const int* __restrict__ rowptr, const int* __restrict__ col,
    const float* __restrict__ b, float* __restrict__ out, int n){
  __shared__ __align__(16) int   colS[4][MAXD];
  __shared__ __align__(16) float wS[4][MAXD];
  int wave = threadIdx.x >> 6, t = threadIdx.x & 63;
  int i = blockIdx.x * 4 + wave; if (i >= n) i = n - 1;
  int start = rowptr[i];
  int deg = rowptr[i + 1] - start;
  float adv = ald[i];
  bool staged = (deg <= MAXD);

  float ls = 0.f;
  if (staged){
    for (int j = t; j < deg; j += 64){
      int s = col[start + j];
      colS[wave][j] = s;
      float w = __expf(leaky(als[s] + adv));
      wS[wave][j] = w;
      ls += w;
    }
  } else {
    for (int j = t; j < deg; j += 64) ls += __expf(leaky(als[col[start + j]] + adv));
  }
  #pragma unroll
  for (int off = 32; off >= 1; off >>= 1) ls += __shfl_down(ls, off, 64);
  float inv = 1.f / (__shfl(ls, 0, 64) + 1e-16f);
  __syncthreads();

  int e2 = t >> 5, l32 = t & 31;
  int f = l32 * 8;
  const unsigned short* Hrow = Hb + f;
  float a0[8] = {0,0,0,0,0,0,0,0}, a1[8] = {0,0,0,0,0,0,0,0};
  float a2[8] = {0,0,0,0,0,0,0,0}, a3[8] = {0,0,0,0,0,0,0,0};
  if (staged){
    int j = 0;
    for (; j + 7 < deg; j += 8){
      int j0 = j + e2, j1 = j + 2 + e2, j2 = j + 4 + e2, j3 = j + 6 + e2;
      int s0 = colS[wave][j0], s1 = colS[wave][j1], s2 = colS[wave][j2], s3 = colS[wave][j3];
      float w0 = wS[wave][j0], w1 = wS[wave][j1], w2 = wS[wave][j2], w3 = wS[wave][j3];
      u16x8 h0 = *(const u16x8*)(Hrow + (size_t)s0 * FDIM);
      u16x8 h1 = *(const u16x8*)(Hrow + (size_t)s1 * FDIM);
      u16x8 h2 = *(const u16x8*)(Hrow + (size_t)s2 * FDIM);
      u16x8 h3 = *(const u16x8*)(Hrow + (size_t)s3 * FDIM);
      #pragma unroll
      for (int k = 0; k < 8; ++k){
        a0[k] += bf2f(h0[k]) * w0; a1[k] += bf2f(h1[k]) * w1;
        a2[k] += bf2f(h2[k]) * w2; a3[k] += bf2f(h3[k]) * w3;
      }
    }
    for (; j + 3 < deg; j += 4){
      int j0 = j + e2, j1 = j + 2 + e2;
      int s0 = colS[wave][j0], s1 = colS[wave][j1];
      float w0 = wS[wave][j0], w1 = wS[wave][j1];
      u16x8 h0 = *(const u16x8*)(Hrow + (size_t)s0 * FDIM);
      u16x8 h1 = *(const u16x8*)(Hrow + (size_t)s1 * FDIM);
      #pragma unroll
      for (int k = 0; k < 8; ++k){ a0[k] += bf2f(h0[k]) * w0; a1[k] += bf2f(h1[k]) * w1; }
    }
    for (; j < deg; j += 2){
      int jj = j + e2;
      if (jj < deg){
        int s = colS[wave][jj]; float w = wS[wave][jj];
        u16x8 hh = *(const u16x8*)(Hrow + (size_t)s * FDIM);
        #pragma unroll
        for (int k = 0; k < 8; ++k) a0[k] += bf2f(hh[k]) * w;
      }
    }
  } else {
    for (int j = e2; j < deg; j += 2){
      int s = col[start + j];
      float w = __expf(leaky(als[s] + adv));
      u16x8 hh = *(const u16x8*)(Hrow + (size_t)s * FDIM);
      #pragma unroll
      for (int k = 0; k < 8; ++k) a0[k] += bf2f(hh[k]) * w;
    }
  }
  float r[8];
  #pragma unroll
  for (int k = 0; k < 8; ++k){
    r[k] = (a0[k] + a1[k]) + (a2[k] + a3[k]);
    r[k] += __shfl_down(r[k], 32, 64);
  }
  if (t < 32){
    float4 bA = *(const float4*)(b + f);
    float4 bB = *(const float4*)(b + f + 4);
    float4 oA = make_float4(r[0]*inv + bA.x, r[1]*inv + bA.y, r[2]*inv + bA.z, r[3]*inv + bA.w);
    float4 oB = make_float4(r[4]*inv + bB.x, r[5]*inv + bB.y, r[6]*inv + bB.z, r[7]*inv + bB.w);
    *(float4*)(out + (size_t)i * FDIM + f) = oA;
    *(float4*)(out + (size_t)i * FDIM + f + 4) = oB;
  }
}

// ------------------------- launch -------------------------
extern "C" void kernel_launch(void* const* d_in, const int* in_sizes, int n_in,
                              void* d_out, int out_size, void* d_ws, size_t ws_size,
                              hipStream_t stream){
  const float* x   = (const float*)d_in[0];
  const int*   ei  = (const int*)d_in[1];
  const float* W1  = (const float*)d_in[2];
  const float* as1 = (const float*)d_in[3];
  const float* ad1 = (const float*)d_in[4];
  const float* b1  = (const float*)d_in[5];
  const float* W2  = (const float*)d_in[6];
  const float* as2 = (const float*)d_in[7];
  const float* ad2 = (const float*)d_in[8];
  const float* b2  = (const float*)d_in[9];
  float* out = (float*)d_out;

  int n = in_sizes[0] / IN_DIM;     // 50000
  int E = in_sizes[1] / 2;          // 800000
  int Mpad = (n + 127) & ~127;      // 50048
  const int* srcIdx = ei;
  const int* dstIdx = ei + E;

  char* ws = (char*)d_ws;
  size_t off = 0;
  auto alloc = [&](size_t bytes) -> void* {
    void* p = ws + off; off += (bytes + 255) & ~(size_t)255; return p;
  };
  unsigned short* bufA = (unsigned short*)alloc((size_t)Mpad * FDIM * 2);  // xb, then out1b
  unsigned short* bufB = (unsigned short*)alloc((size_t)Mpad * FDIM * 2);  // H1b, then H2b
  unsigned short* W1t  = (unsigned short*)alloc(256 * 256 * 2);
  unsigned short* W2t  = (unsigned short*)alloc(256 * 256 * 2);
  // zero block: deg | fill | als2 | ald2 (single memset)
  int*   zeros    = (int*)alloc((size_t)n * 4 * 4);
  int*   deg      = zeros;
  int*   fill     = zeros + n;
  float* als2     = (float*)(zeros + 2 * (size_t)n);
  float* ald2     = (float*)(zeros + 3 * (size_t)n);
  int*   tmp      = (int*)alloc((size_t)n * 4);
  int*   rowptr   = (int*)alloc((size_t)(n + 1) * 4);
  int*   partials = (int*)alloc(1024 * 4);
  int*   col      = (int*)alloc((size_t)(E + n) * 4);
  float* als1     = (float*)alloc((size_t)n * HEADS * 4);
  float* ald1     = (float*)alloc((size_t)n * HEADS * 4);
  (void)ws_size;

  int nb = (n + 255) / 256;
  // CSR build
  hipMemsetAsync(zeros, 0, (size_t)n * 4 * 4, stream);
  k_hist<<<(E + 255) / 256, 256, 0, stream>>>(dstIdx, deg, E);
  k_scanA<<<nb, 256, 0, stream>>>(deg, tmp, partials, n);
  k_scanB<<<1, 1024, 0, stream>>>(partials, nb);
  k_scanC<<<nb, 256, 0, stream>>>(tmp, deg, partials, rowptr, n);
  k_fill<<<(E + n + 255) / 256, 256, 0, stream>>>(srcIdx, dstIdx, rowptr, fill, col, E, n);

  // fused cast + weight transposes
  int castBlocks = (Mpad * (FDIM / 4) + 255) / 256;
  k_castwt<<<castBlocks + 512, 256, 0, stream>>>(x, bufA, n, castBlocks, W1, W1t, W2, W2t);

  dim3 gg(Mpad / 128, FDIM / 128);
  int ga = (n + 3) / 4;
  // layer 1 (attention logits fused into GEMM epilogue)
  k_gemm<<<gg, 256, 0, stream>>>(bufA, W1t, bufB, as1, ad1, als1, ald1, n, 1);  // H1b + als1/ald1
  k_agg1<<<ga, 256, 0, stream>>>(bufB, als1, ald1, rowptr, col, b1, bufA, n);   // out1b (ELU'd, bf16)
  // layer 2
  k_gemm<<<gg, 256, 0, stream>>>(bufA, W2t, bufB, as2, ad2, als2, ald2, n, 0);  // H2b + als2/ald2
  k_agg2<<<ga, 256, 0, stream>>>(bufB, als2, ald2, rowptr, col, b2, out, n);
}

// Round 8
// 395.202 us; speedup vs baseline: 2.0259x; 1.0461x over previous
//
#include <hip/hip_runtime.h>
#include <math.h>

#define IN_DIM 256
#define FDIM 256      // HEADS*HID == OUT == 256
#define HEADS 4
#define NEG 0.2f
#define MAXD 96       // per-node staged edge cap; in-deg ~ Poisson(16)+1, P(>96) ~ 0

typedef __attribute__((ext_vector_type(8))) short bf16x8;
typedef __attribute__((ext_vector_type(8))) unsigned short u16x8;
typedef __attribute__((ext_vector_type(4))) float f32x4;

__device__ __forceinline__ float leaky(float x){ return x > 0.f ? x : NEG * x; }

__device__ __forceinline__ unsigned short f2bf(float f){
  unsigned int u = __float_as_uint(f);
  unsigned int r = u + 0x7fffu + ((u >> 16) & 1u);   // round-to-nearest-even
  return (unsigned short)(r >> 16);
}
__device__ __forceinline__ float bf2f(unsigned short s){
  return __uint_as_float(((unsigned int)s) << 16);
}

__device__ __forceinline__ float4 bcast4(float4 v){
  return make_float4(__shfl(v.x,0,64), __shfl(v.y,0,64), __shfl(v.z,0,64), __shfl(v.w,0,64));
}
__device__ __forceinline__ float comp4(float4 v, int h){
  return h==0 ? v.x : h==1 ? v.y : h==2 ? v.z : v.w;
}

__device__ __forceinline__ void gld_lds16(const void* g, void* l){
  __builtin_amdgcn_global_load_lds((const __attribute__((address_space(1))) unsigned int*)g,
                                   (__attribute__((address_space(3))) unsigned int*)l, 16, 0, 0);
}

// ------------------------- fused: x cast + weight transpose + degree histogram -------------------------
__global__ void k_castwt(const float* __restrict__ x, unsigned short* __restrict__ xb, int M, int castBlocks,
                         const float* __restrict__ W1, unsigned short* __restrict__ W1t,
                         const float* __restrict__ W2, unsigned short* __restrict__ W2t,
                         const int* __restrict__ dst, int* __restrict__ deg, int E){
  int b = blockIdx.x;
  if (b < castBlocks){
    int idx = b * 256 + threadIdx.x;   // one ushort4 group per thread
    int row = idx >> 6;
    float4 v = make_float4(0.f, 0.f, 0.f, 0.f);
    if (row < M) v = *(const float4*)(x + (size_t)idx * 4);
    ushort4 o;
    o.x = f2bf(v.x); o.y = f2bf(v.y); o.z = f2bf(v.z); o.w = f2bf(v.w);
    *(ushort4*)(xb + (size_t)idx * 4) = o;
  } else if (b < castBlocks + 512){
    int bb = b - castBlocks;
    const float* W = (bb < 256) ? W1 : W2;
    unsigned short* Wt = (bb < 256) ? W1t : W2t;
    int nn = bb & 255, k = threadIdx.x;
    Wt[nn * 256 + k] = f2bf(W[k * 256 + nn]);
  } else {
    int e = (b - castBlocks - 512) * 256 + threadIdx.x;
    if (e < E) atomicAdd(&deg[dst[e]], 1);
  }
}

// ------------------------- CSR build -------------------------
__global__ void k_scanA(const int* __restrict__ deg, int* tmp, int* partials, int n){
  __shared__ int sm[256];
  int i = blockIdx.x * 256 + threadIdx.x;
  int v = (i < n) ? deg[i] + 1 : 0;     // +1: self loop
  sm[threadIdx.x] = v; __syncthreads();
  for (int off = 1; off < 256; off <<= 1){
    int x = (threadIdx.x >= off) ? sm[threadIdx.x - off] : 0;
    __syncthreads();
    sm[threadIdx.x] += x;
    __syncthreads();
  }
  if (i < n) tmp[i] = sm[threadIdx.x];            // inclusive within block
  if (threadIdx.x == 255) partials[blockIdx.x] = sm[255];
}

// scanC with inline partials-prefix reduction (replaces the old scanB+scanC pair).
// Each block sums partials[0..bid-1] (nb <= 256) itself: one wave-reduce + LDS.
__global__ void k_scanC(const int* __restrict__ tmp, const int* __restrict__ deg,
                        const int* __restrict__ partials, int* rowptr, int n, int nb){
  __shared__ int ws[4];
  int bid = blockIdx.x, t = threadIdx.x;
  int lane = t & 63, w = t >> 6;
  int v = (t < bid && t < nb) ? partials[t] : 0;
  #pragma unroll
  for (int off = 32; off >= 1; off >>= 1) v += __shfl_down(v, off, 64);
  if (lane == 0) ws[w] = v;
  __syncthreads();
  int prefix = ws[0] + ws[1] + ws[2] + ws[3];
  int i = bid * 256 + t;
  if (i < n){
    int incl = tmp[i] + prefix;
    rowptr[i] = incl - (deg[i] + 1);
    if (i == n - 1) rowptr[n] = incl;             // total = E + n
  }
}

__global__ void k_fill(const int* __restrict__ src, const int* __restrict__ dst,
                       const int* __restrict__ rowptr, int* fill, int* col, int E, int n){
  int e = blockIdx.x * blockDim.x + threadIdx.x;
  if (e < E + n){
    int s, d;
    if (e < E){ s = src[e]; d = dst[e]; } else { s = d = e - E; }
    int pos = atomicAdd(&fill[d], 1);
    col[rowptr[d] + pos] = s;
  }
}

// ------------------------- bf16 MFMA GEMM: C[M,256] = A[M,256] @ Bt[256,256]^T -------------------------
__global__ __launch_bounds__(256) void k_gemm(const unsigned short* __restrict__ A,
                                              const unsigned short* __restrict__ Bt,
                                              unsigned short* __restrict__ C){
  __shared__ __align__(16) unsigned short sh[8192];   // As = sh[0:4096], Bs = sh[4096:8192] (shorts)
  unsigned short* As = sh;
  unsigned short* Bs = sh + 4096;
  int tid = threadIdx.x;
  int lane = tid & 63, wave = tid >> 6;
  int rowBase = blockIdx.x * 128, colBase = blockIdx.y * 128;
  int wr = (wave & 1) * 64, wc = (wave >> 1) * 64;

  f32x4 acc[4][4] = {};
  int c0 = tid, c1 = tid + 256;
  int r0 = c0 >> 2, kc0 = (c0 & 3) * 8;
  int r1 = c1 >> 2, kc1 = (c1 & 3) * 8;
  int m0 = lane & 15, kq = (lane >> 4) * 8;

  for (int k0 = 0; k0 < 256; k0 += 32){
    gld_lds16(A  + (size_t)(rowBase + r0) * 256 + k0 + kc0, (char*)As + c0 * 16);
    gld_lds16(A  + (size_t)(rowBase + r1) * 256 + k0 + kc1, (char*)As + c1 * 16);
    gld_lds16(Bt + (size_t)(colBase + r0) * 256 + k0 + kc0, (char*)Bs + c0 * 16);
    gld_lds16(Bt + (size_t)(colBase + r1) * 256 + k0 + kc1, (char*)Bs + c1 * 16);
    __syncthreads();
    bf16x8 af[4], bfr[4];
    #pragma unroll
    for (int it = 0; it < 4; ++it)
      af[it] = *(const bf16x8*)(As + (wr + it * 16 + m0) * 32 + kq);
    #pragma unroll
    for (int jt = 0; jt < 4; ++jt)
      bfr[jt] = *(const bf16x8*)(Bs + (wc + jt * 16 + m0) * 32 + kq);
    #pragma unroll
    for (int it = 0; it < 4; ++it)
      #pragma unroll
      for (int jt = 0; jt < 4; ++jt)
        acc[it][jt] = __builtin_amdgcn_mfma_f32_16x16x32_bf16(af[it], bfr[jt], acc[it][jt], 0, 0, 0);
    __syncthreads();
  }
  // epilogue: repack C/D frags (col=lane&15, row=(lane>>4)*4+reg) through LDS -> 16B stores.
  int cq = lane >> 4, cm = lane & 15;
  #pragma unroll
  for (int p = 0; p < 2; ++p){
    if ((wave >> 1) == p){
      #pragma unroll
      for (int it = 0; it < 4; ++it)
        #pragma unroll
        for (int jt = 0; jt < 4; ++jt)
          #pragma unroll
          for (int r = 0; r < 4; ++r)
            sh[(wr + it * 16 + cq * 4 + r) * 64 + jt * 16 + cm] = f2bf(acc[it][jt][r]);
    }
    __syncthreads();
    #pragma unroll
    for (int q = 0; q < 4; ++q){
      int id = tid + q * 256;            // 0..1023
      int r = id >> 3, sg = id & 7;      // row 0..127, 8-short segment 0..7
      u16x8 v = *(const u16x8*)(sh + r * 64 + sg * 8);
      *(u16x8*)(C + (size_t)(rowBase + r) * 256 + colBase + p * 64 + sg * 8) = v;
    }
    __syncthreads();
  }
}

// ------------------------- attention logits: 4 nodes/block, wave per node -------------------------
__global__ __launch_bounds__(256) void k_al4(const unsigned short* __restrict__ Hb,
                      const float* __restrict__ as_, const float* __restrict__ ad_,
                      float* als, float* ald, int n){
  int wave = threadIdx.x >> 6, lane = threadIdx.x & 63;
  int i = blockIdx.x * 4 + wave; if (i >= n) i = n - 1;
  int f = lane * 4;
  ushort4 hv = *(const ushort4*)(Hb + (size_t)i * FDIM + f);
  float4 av = *(const float4*)(as_ + f);
  float4 dv = *(const float4*)(ad_ + f);
  float h0 = bf2f(hv.x), h1 = bf2f(hv.y), h2 = bf2f(hv.z), h3 = bf2f(hv.w);
  float ps = h0*av.x + h1*av.y + h2*av.z + h3*av.w;
  float pd = h0*dv.x + h1*dv.y + h2*dv.z + h3*dv.w;
  #pragma unroll
  for (int off = 8; off >= 1; off >>= 1){       // reduce within 16-lane head groups
    ps += __shfl_down(ps, off, 16);
    pd += __shfl_down(pd, off, 16);
  }
  if ((lane & 15) == 0){
    int h = lane >> 4;
    als[i * HEADS + h] = ps; ald[i * HEADS + h] = pd;
  }
}

__global__ __launch_bounds__(256) void k_al1(const unsigned short* __restrict__ Hb,
                      const float* __restrict__ as_, const float* __restrict__ ad_,
                      float* als, float* ald, int n){
  int wave = threadIdx.x >> 6, lane = threadIdx.x & 63;
  int i = blockIdx.x * 4 + wave; if (i >= n) i = n - 1;
  int f = lane * 4;
  ushort4 hv = *(const ushort4*)(Hb + (size_t)i * FDIM + f);
  float4 av = *(const float4*)(as_ + f);
  float4 dv = *(const float4*)(ad_ + f);
  float h0 = bf2f(hv.x), h1 = bf2f(hv.y), h2 = bf2f(hv.z), h3 = bf2f(hv.w);
  float ps = h0*av.x + h1*av.y + h2*av.z + h3*av.w;
  float pd = h0*dv.x + h1*dv.y + h2*dv.z + h3*dv.w;
  #pragma unroll
  for (int off = 32; off >= 1; off >>= 1){
    ps += __shfl_down(ps, off, 64);
    pd += __shfl_down(pd, off, 64);
  }
  if (lane == 0){ als[i] = ps; ald[i] = pd; }
}

// ------------------------- layer-1 aggregation: 4 nodes/block, wave per node -------------------------
// softmax without max-subtraction (logits ~ +-3 here; mathematically identical)
// node range [i0, nEnd): split across 2 dispatches for profile visibility.
__global__ __launch_bounds__(256) void k_agg1(const unsigned short* __restrict__ Hb,
    const float* __restrict__ als, const float* __restrict__ ald,
    const int* __restrict__ rowptr, const int* __restrict__ col,
    const float* __restrict__ b, unsigned short* __restrict__ outb, int i0, int nEnd){
  __shared__ __align__(16) int   colS[4][MAXD];
  __shared__ __align__(16) float wS[4][MAXD][4];
  int wave = threadIdx.x >> 6, t = threadIdx.x & 63;
  int i = i0 + blockIdx.x * 4 + wave; if (i >= nEnd) i = nEnd - 1;
  int start = rowptr[i];
  int deg = rowptr[i + 1] - start;
  float4 adv = *(const float4*)(ald + (size_t)i * 4);
  bool staged = (deg <= MAXD);

  // phase A: stage col + softmax weights, accumulate per-head sums
  float4 ls = make_float4(0.f, 0.f, 0.f, 0.f);
  if (staged){
    for (int j = t; j < deg; j += 64){
      int s = col[start + j];
      colS[wave][j] = s;
      float4 a = *(const float4*)(als + (size_t)s * 4);
      float4 w = make_float4(__expf(leaky(a.x + adv.x)), __expf(leaky(a.y + adv.y)),
                             __expf(leaky(a.z + adv.z)), __expf(leaky(a.w + adv.w)));
      *(float4*)(&wS[wave][j][0]) = w;
      ls.x += w.x; ls.y += w.y; ls.z += w.z; ls.w += w.w;
    }
  } else {
    for (int j = t; j < deg; j += 64){
      int s = col[start + j];
      float4 a = *(const float4*)(als + (size_t)s * 4);
      ls.x += __expf(leaky(a.x + adv.x)); ls.y += __expf(leaky(a.y + adv.y));
      ls.z += __expf(leaky(a.z + adv.z)); ls.w += __expf(leaky(a.w + adv.w));
    }
  }
  #pragma unroll
  for (int off = 32; off >= 1; off >>= 1) ls = make_float4(
      ls.x + __shfl_down(ls.x, off, 64), ls.y + __shfl_down(ls.y, off, 64),
      ls.z + __shfl_down(ls.z, off, 64), ls.w + __shfl_down(ls.w, off, 64));
  float4 d4 = bcast4(ls);
  __syncthreads();

  // phase C: half-wave per edge, 8 feats/lane (16B loads)
  int e2 = t >> 5, l32 = t & 31;
  int h = l32 >> 3, f = l32 * 8;
  float inv = 1.f / (comp4(d4, h) + 1e-16f);
  const unsigned short* Hrow = Hb + f;
  float a0[8] = {0,0,0,0,0,0,0,0}, a1[8] = {0,0,0,0,0,0,0,0};
  if (staged){
    int j = 0;
    for (; j + 3 < deg; j += 4){
      int j0 = j + e2, j1 = j + 2 + e2;
      int s0 = colS[wave][j0], s1 = colS[wave][j1];
      float w0 = wS[wave][j0][h], w1 = wS[wave][j1][h];
      u16x8 h0 = *(const u16x8*)(Hrow + (size_t)s0 * FDIM);
      u16x8 h1 = *(const u16x8*)(Hrow + (size_t)s1 * FDIM);
      #pragma unroll
      for (int k = 0; k < 8; ++k){ a0[k] += bf2f(h0[k]) * w0; a1[k] += bf2f(h1[k]) * w1; }
    }
    for (; j < deg; j += 2){
      int jj = j + e2;
      if (jj < deg){
        int s = colS[wave][jj]; float w = wS[wave][jj][h];
        u16x8 hh = *(const u16x8*)(Hrow + (size_t)s * FDIM);
        #pragma unroll
        for (int k = 0; k < 8; ++k) a0[k] += bf2f(hh[k]) * w;
      }
    }
  } else {
    float adh = comp4(adv, h);
    for (int j = e2; j < deg; j += 2){
      int s = col[start + j];
      float w = __expf(leaky(als[(size_t)s * 4 + h] + adh));
      u16x8 hh = *(const u16x8*)(Hrow + (size_t)s * FDIM);
      #pragma unroll
      for (int k = 0; k < 8; ++k) a0[k] += bf2f(hh[k]) * w;
    }
  }
  float r[8];
  #pragma unroll
  for (int k = 0; k < 8; ++k){
    r[k] = a0[k] + a1[k];
    r[k] += __shfl_down(r[k], 32, 64);
  }
  if (t < 32){
    float4 bA = *(const float4*)(b + f);
    float4 bB = *(const float4*)(b + f + 4);
    float bb[8] = {bA.x, bA.y, bA.z, bA.w, bB.x, bB.y, bB.z, bB.w};
    u16x8 o;
    #pragma unroll
    for (int k = 0; k < 8; ++k){
      float v = r[k] * inv + bb[k];
      v = (v > 0.f) ? v : (__expf(v) - 1.f);    // ELU
      o[k] = f2bf(v);
    }
    *(u16x8*)(outb + (size_t)i * FDIM + f) = o;
  }
}

// ------------------------- layer-2 aggregation: 4 nodes/block, wave per node, fp32 out -------------------------
__global__ __launch_bounds__(256) void k_agg2(const unsigned short* __restrict__ Hb,
    const float* __restrict__ als, const float* __restrict__ ald,
    const int* __restrict__ rowptr, const int* __restrict__ col,
    const float* __restrict__ b, float* __restrict__ out, int i0, int nEnd){
  __shared__ __align__(16) int   colS[4][MAXD];
  __shared__ __align__(16) float wS[4][MAXD];
  int wave = threadIdx.x >> 6, t = threadIdx.x & 63;
  int i = i0 + blockIdx.x * 4 + wave; if (i >= nEnd) i = nEnd - 1;
  int start = rowptr[i];
  int deg = rowptr[i + 1] - start;
  float adv = ald[i];
  bool staged = (deg <= MAXD);

  float ls = 0.f;
  if (staged){
    for (int j = t; j < deg; j += 64){
      int s = col[start + j];
      colS[wave][j] = s;
      float w = __expf(leaky(als[s] + adv));
      wS[wave][j] = w;
      ls += w;
    }
  } else {
    for (int j = t; j < deg; j += 64) ls += __expf(leaky(als[col[start + j]] + adv));
  }
  #pragma unroll
  for (int off = 32; off >= 1; off >>= 1) ls += __shfl_down(ls, off, 64);
  float inv = 1.f / (__shfl(ls, 0, 64) + 1e-16f);
  __syncthreads();

  int e2 = t >> 5, l32 = t & 31;
  int f = l32 * 8;
  const unsigned short* Hrow = Hb + f;
  float a0[8] = {0,0,0,0,0,0,0,0}, a1[8] = {0,0,0,0,0,0,0,0};
  if (staged){
    int j = 0;
    for (; j + 3 < deg; j += 4){
      int j0 = j + e2, j1 = j + 2 + e2;
      int s0 = colS[wave][j0], s1 = colS[wave][j1];
      float w0 = wS[wave][j0], w1 = wS[wave][j1];
      u16x8 h0 = *(const u16x8*)(Hrow + (size_t)s0 * FDIM);
      u16x8 h1 = *(const u16x8*)(Hrow + (size_t)s1 * FDIM);
      #pragma unroll
      for (int k = 0; k < 8; ++k){ a0[k] += bf2f(h0[k]) * w0; a1[k] += bf2f(h1[k]) * w1; }
    }
    for (; j < deg; j += 2){
      int jj = j + e2;
      if (jj < deg){
        int s = colS[wave][jj]; float w = wS[wave][jj];
        u16x8 hh = *(const u16x8*)(Hrow + (size_t)s * FDIM);
        #pragma unroll
        for (int k = 0; k < 8; ++k) a0[k] += bf2f(hh[k]) * w;
      }
    }
  } else {
    for (int j = e2; j < deg; j += 2){
      int s = col[start + j];
      float w = __expf(leaky(als[s] + adv));
      u16x8 hh = *(const u16x8*)(Hrow + (size_t)s * FDIM);
      #pragma unroll
      for (int k = 0; k < 8; ++k) a0[k] += bf2f(hh[k]) * w;
    }
  }
  float r[8];
  #pragma unroll
  for (int k = 0; k < 8; ++k){
    r[k] = a0[k] + a1[k];
    r[k] += __shfl_down(r[k], 32, 64);
  }
  if (t < 32){
    float4 bA = *(const float4*)(b + f);
    float4 bB = *(const float4*)(b + f + 4);
    float4 oA = make_float4(r[0]*inv + bA.x, r[1]*inv + bA.y, r[2]*inv + bA.z, r[3]*inv + bA.w);
    float4 oB = make_float4(r[4]*inv + bB.x, r[5]*inv + bB.y, r[6]*inv + bB.z, r[7]*inv + bB.w);
    *(float4*)(out + (size_t)i * FDIM + f) = oA;
    *(float4*)(out + (size_t)i * FDIM + f + 4) = oB;
  }
}

// ------------------------- launch -------------------------
extern "C" void kernel_launch(void* const* d_in, const int* in_sizes, int n_in,
                              void* d_out, int out_size, void* d_ws, size_t ws_size,
                              hipStream_t stream){
  const float* x   = (const float*)d_in[0];
  const int*   ei  = (const int*)d_in[1];
  const float* W1  = (const float*)d_in[2];
  const float* as1 = (const float*)d_in[3];
  const float* ad1 = (const float*)d_in[4];
  const float* b1  = (const float*)d_in[5];
  const float* W2  = (const float*)d_in[6];
  const float* as2 = (const float*)d_in[7];
  const float* ad2 = (const float*)d_in[8];
  const float* b2  = (const float*)d_in[9];
  float* out = (float*)d_out;

  int n = in_sizes[0] / IN_DIM;     // 50000
  int E = in_sizes[1] / 2;          // 800000
  int Mpad = (n + 127) & ~127;      // 50048
  const int* srcIdx = ei;
  const int* dstIdx = ei + E;

  char* ws = (char*)d_ws;
  size_t off = 0;
  auto alloc = [&](size_t bytes) -> void* {
    void* p = ws + off; off += (bytes + 255) & ~(size_t)255; return p;
  };
  unsigned short* bufA = (unsigned short*)alloc((size_t)Mpad * FDIM * 2);  // xb, then out1b
  unsigned short* bufB = (unsigned short*)alloc((size_t)Mpad * FDIM * 2);  // H1b, then H2b
  unsigned short* W1t  = (unsigned short*)alloc(256 * 256 * 2);
  unsigned short* W2t  = (unsigned short*)alloc(256 * 256 * 2);
  // zero block: deg | fill (single memset)
  int*   zeros    = (int*)alloc((size_t)n * 2 * 4);
  int*   deg      = zeros;
  int*   fill     = zeros + n;
  int*   tmp      = (int*)alloc((size_t)n * 4);
  int*   rowptr   = (int*)alloc((size_t)(n + 1) * 4);
  int*   partials = (int*)alloc(1024 * 4);
  int*   col      = (int*)alloc((size_t)(E + n) * 4);
  float* als1     = (float*)alloc((size_t)n * HEADS * 4);
  float* ald1     = (float*)alloc((size_t)n * HEADS * 4);
  float* als2     = (float*)alloc((size_t)n * 4);
  float* ald2     = (float*)alloc((size_t)n * 4);
  (void)ws_size;

  int nb = (n + 255) / 256;
  hipMemsetAsync(zeros, 0, (size_t)n * 2 * 4, stream);

  // fused cast + weight transposes + degree histogram
  int castBlocks = (Mpad * (FDIM / 4) + 255) / 256;
  int histBlocks = (E + 255) / 256;
  k_castwt<<<castBlocks + 512 + histBlocks, 256, 0, stream>>>(
      x, bufA, n, castBlocks, W1, W1t, W2, W2t, dstIdx, deg, E);

  // CSR build (scanB folded into scanC)
  k_scanA<<<nb, 256, 0, stream>>>(deg, tmp, partials, n);
  k_scanC<<<nb, 256, 0, stream>>>(tmp, deg, partials, rowptr, n, nb);
  k_fill<<<(E + n + 255) / 256, 256, 0, stream>>>(srcIdx, dstIdx, rowptr, fill, col, E, n);

  dim3 gg(Mpad / 128, FDIM / 128);
  int ga = (n + 3) / 4;
  int nA = 25000;                       // split point (multiple of 4)
  int gaA = nA / 4, gaB = (n - nA + 3) / 4;
  // layer 1
  k_gemm<<<gg, 256, 0, stream>>>(bufA, W1t, bufB);                           // H1b
  k_al4<<<ga, 256, 0, stream>>>(bufB, as1, ad1, als1, ald1, n);
  k_agg1<<<gaA, 256, 0, stream>>>(bufB, als1, ald1, rowptr, col, b1, bufA, 0, nA);
  k_agg1<<<gaB, 256, 0, stream>>>(bufB, als1, ald1, rowptr, col, b1, bufA, nA, n);
  // layer 2
  k_gemm<<<gg, 256, 0, stream>>>(bufA, W2t, bufB);                           // H2b
  k_al1<<<ga, 256, 0, stream>>>(bufB, as2, ad2, als2, ald2, n);
  k_agg2<<<gaA, 256, 0, stream>>>(bufB, als2, ald2, rowptr, col, b2, out, 0, nA);
  k_agg2<<<gaB, 256, 0, stream>>>(bufB, als2, ald2, rowptr, col, b2, out, nA, n);
}